// Round 1
// baseline (17756.406 us; speedup 1.0000x reference)
//
#include <hip/hip_runtime.h>
#include <hip/hip_bf16.h>
#include <math.h>

using bf16 = __hip_bfloat16;
using short8 = __attribute__((ext_vector_type(8))) short;
using f32x4  = __attribute__((ext_vector_type(4))) float;

#define B_     128
#define T_     64
#define EMB_   1536
#define ACT_   12
#define STOCH_ 32
#define DETER_ 1024
#define HID_   1024
#define GRUN_  3072
#define GRUK_  2048
#define OBSK_  2560
#define OUTW_  1216   // 6*STOCH + DETER

// canonical f32 param block offsets (floats)
#define PW1   0
#define Pb1   45056
#define Pg1   46080
#define Pbn1  47104
#define Pbg   48128
#define Pgg   51200
#define Pbng  54272
#define Pb3   57344
#define Pg3   62464
#define Pbn3  67584
#define Pb4   72704
#define Pb5   73024
#define Pg5   74048
#define Pbn5  75072
#define Pb6   76096
#define PW4   76160
#define PW6   403840
#define PTOT  469376

#define GRID_ 192   // persistent blocks: 1/CU guaranteed co-resident (256 CUs)

__device__ inline float bf2f(bf16 v){ return __bfloat162float(v); }
__device__ inline bf16  f2bf(float v){ return __float2bfloat16(v); }
__device__ inline float elu_(float x){ return x > 0.f ? x : expm1f(x); }
__device__ inline float sigm_(float x){ return 1.f/(1.f+expf(-x)); }
__device__ inline float softplus_(float x){ return fmaxf(x,0.f) + log1pf(expf(-fabsf(x))); }
__device__ inline void stout(void* out, int dt, size_t i, float v){
  if(dt) ((bf16*)out)[i] = f2bf(v); else ((float*)out)[i] = v;
}
__device__ inline float maskv(const void* isf, int enc, int idx){
  float fv;
  if(enc==0)      fv = (float)((const int*)isf)[idx];
  else if(enc==1) fv = (float)((const unsigned char*)isf)[idx];
  else if(enc==2) fv = bf2f(((const bf16*)isf)[idx]);
  else            fv = ((const float*)isf)[idx];
  return (fv != 0.f) ? 0.f : 1.f;
}

// 256-thread block reduction of two values (sum, sumsq)
__device__ inline void block_reduce2(float& a, float& b, float* sm){
  __syncthreads();
  for(int off=32; off>0; off>>=1){
    a += __shfl_down(a, off);
    b += __shfl_down(b, off);
  }
  int w = threadIdx.x >> 6;
  if((threadIdx.x & 63) == 0){ sm[2*w] = a; sm[2*w+1] = b; }
  __syncthreads();
  a = sm[0]+sm[2]+sm[4]+sm[6];
  b = sm[1]+sm[3]+sm[5]+sm[7];
}

// ---- device-wide sense-reversing barrier (agent-scope atomics + fences) ----
// bar[0]=arrive counter, bar[1]=release flag. All GRID_ blocks co-resident
// (1 block/CU, grid=192 <= 256 CUs). Timeout converts any residency bug
// into wrong-answer termination instead of a hang.
__device__ inline void gbar(int* bar, int& sense){
  __syncthreads();
  if(threadIdx.x == 0){
    int s = sense ^ 1; sense = s;
    __threadfence();   // release: write back this XCD's dirty L2 lines
    int old = __hip_atomic_fetch_add(&bar[0], 1, __ATOMIC_RELAXED, __HIP_MEMORY_SCOPE_AGENT);
    if(old == GRID_-1){
      __hip_atomic_store(&bar[0], 0, __ATOMIC_RELAXED, __HIP_MEMORY_SCOPE_AGENT);
      __hip_atomic_store(&bar[1], s, __ATOMIC_RELEASE, __HIP_MEMORY_SCOPE_AGENT);
    } else {
      int it = 0;
      while(__hip_atomic_load(&bar[1], __ATOMIC_RELAXED, __HIP_MEMORY_SCOPE_AGENT) != s){
        __builtin_amdgcn_s_sleep(2);
        if(++it > (1<<20)) break;   // ~0.3 s safety valve
      }
    }
    __threadfence();   // acquire: invalidate stale L1/L2 before phase reads
  }
  __syncthreads();
}

// ---- detect float dtype from embed buffer: dflag[0] = 1 if bf16, 0 if f32 ----
__global__ void k_detect_dtype(const unsigned short* emb, int* dflag, int* bar){
  __shared__ int cnt;
  if(threadIdx.x < 2) bar[threadIdx.x] = 0;   // zero barrier state each launch
  if(threadIdx.x==0) cnt = 0;
  __syncthreads();
  int c = 0;
  for(int i=threadIdx.x; i<2048; i+=256){
    unsigned short u = emb[2*i];
    int exp8 = (u >> 7) & 0xFF;
    if(exp8 > 140) c++;
  }
  atomicAdd(&cnt, c);
  __syncthreads();
  if(threadIdx.x==0) dflag[0] = (cnt < 100) ? 1 : 0;
}

// ---- detect is_first encoding: dflag[1] = 0 int32, 1 uint8, 2 bf16, 3 f32 ----
__global__ void k_detect_isf(const unsigned char* isf, int* dflag){
  __shared__ int f_bf, f_f32, f_u8;
  if(threadIdx.x==0){ f_bf=0; f_f32=0; f_u8=0; }
  __syncthreads();
  for(int i=threadIdx.x; i<B_*T_; i+=256){
    unsigned char c = isf[i];
    if(c == 0x3F){
      if((i & 3) == 1) atomicOr(&f_bf, 1);
      else if((i & 3) == 3) atomicOr(&f_f32, 1);
    }
    if(c == 1 && (i & 3) != 0) atomicOr(&f_u8, 1);
  }
  __syncthreads();
  if(threadIdx.x==0)
    dflag[1] = f_bf ? 2 : (f_f32 ? 3 : (f_u8 ? 1 : 0));
}

// ---- batched param conversion -> canonical f32 block ----
struct PDesc { const void* src[17]; int cum[18]; };
__global__ __launch_bounds__(256) void k_params(PDesc pd, float* dst, const int* dflag){
  int g = blockIdx.x*256 + threadIdx.x;
  if(g >= PTOT) return;
  int dt = dflag[0];
  int s = 0;
  while(g >= pd.cum[s+1]) s++;
  int off = g - pd.cum[s];
  dst[g] = dt ? bf2f(((const bf16*)pd.src[s])[off]) : ((const float*)pd.src[s])[off];
}

__global__ void k_cvt_bf(const void* src, bf16* dst, int n, const int* dflag){
  int dt = dflag[0];
  int i0 = (blockIdx.x*256 + threadIdx.x)*4;
  #pragma unroll
  for(int k=0;k<4;k++){
    int i = i0+k;
    if(i < n) dst[i] = dt ? ((const bf16*)src)[i] : f2bf(((const float*)src)[i]);
  }
}

__global__ void k_cvt_f(const void* src, float* dst, int n, const int* dflag){
  int dt = dflag[0];
  int i0 = (blockIdx.x*256 + threadIdx.x)*4;
  #pragma unroll
  for(int k=0;k<4;k++){
    int i = i0+k;
    if(i < n) dst[i] = dt ? bf2f(((const bf16*)src)[i]) : ((const float*)src)[i];
  }
}

// ---- tiled transpose: src[K][N] -> dst[N][K] (bf16 canonical), head = blockIdx.y ----
__global__ __launch_bounds__(256) void k_transpose(const void* src, bf16* dst, int K, int N, const int* dflag){
  __shared__ unsigned short t[64][72];
  int dt = dflag[0];
  int tilesN = N/64;
  int tk = blockIdx.x / tilesN, tn = blockIdx.x % tilesN;
  size_t hoff = (size_t)blockIdx.y * K * N;
  unsigned short* d = (unsigned short*)dst + hoff;
  int tx = threadIdx.x & 63, ty0 = threadIdx.x >> 6;
  int k0 = tk*64, n0 = tn*64;
  #pragma unroll
  for(int i=0;i<16;i++){
    int ty = ty0*16+i;
    size_t off = hoff + (size_t)(k0+ty)*N + n0+tx;
    unsigned short v;
    if(dt) v = ((const unsigned short*)src)[off];
    else { bf16 b = f2bf(((const float*)src)[off]); v = *(unsigned short*)&b; }
    t[ty][tx] = v;
  }
  __syncthreads();
  #pragma unroll
  for(int i=0;i<16;i++){ int ty = ty0*16+i; d[(size_t)(n0+ty)*K + k0+tx] = t[tx][ty]; }
}

// ---- MFMA GEMM tile: 128x32 output, K split over 4 waves, LDS reduce ----
// (verbatim math from the proven k_gemm; now a device function for phases)
__device__ void gemm_tile(const bf16* A0, const bf16* A1, int s0, int s1, int split,
                          const bf16* BT, int ldb, int N, int k0, int kc,
                          float* Cdst, float* red)
{
  int tid = threadIdx.x;
  int wave = tid >> 6, lane = tid & 63;
  int quad = lane >> 4, lo = lane & 15;
  int kw0 = k0 + wave*(kc>>2), kw1 = kw0 + (kc>>2);
  f32x4 acc[8][2];
  #pragma unroll
  for(int rf=0;rf<8;rf++){ acc[rf][0]=(f32x4)0.f; acc[rf][1]=(f32x4)0.f; }
  for(int kk=kw0; kk<kw1; kk+=32){
    int kf = kk + quad*8;
    const bf16* Ab; int str, ko;
    if(kf < split){ Ab=A0; str=s0; ko=kf; } else { Ab=A1; str=s1; ko=kf-split; }
    short8 af[8], bfg[2];
    #pragma unroll
    for(int rf=0;rf<8;rf++)
      af[rf] = *(const short8*)(const void*)(Ab + (size_t)(16*rf+lo)*str + ko);
    #pragma unroll
    for(int c=0;c<2;c++)
      bfg[c] = *(const short8*)(const void*)(BT + (size_t)(16*c+lo)*ldb + kf);
    #pragma unroll
    for(int rf=0;rf<8;rf++){
      acc[rf][0] = __builtin_amdgcn_mfma_f32_16x16x32_bf16(af[rf], bfg[0], acc[rf][0], 0,0,0);
      acc[rf][1] = __builtin_amdgcn_mfma_f32_16x16x32_bf16(af[rf], bfg[1], acc[rf][1], 0,0,0);
    }
  }
  // cross-wave reduce: waves 2,3 dump -> waves 0,1 add -> waves 0,1 dump -> all sum pairs
  if(wave >= 2){
    #pragma unroll
    for(int rf=0;rf<8;rf++)
      #pragma unroll
      for(int c=0;c<2;c++)
        *(f32x4*)&red[(((wave-2)*16) + rf*2 + c)*256 + lane*4] = acc[rf][c];
  }
  __syncthreads();
  if(wave < 2){
    #pragma unroll
    for(int rf=0;rf<8;rf++)
      #pragma unroll
      for(int c=0;c<2;c++)
        acc[rf][c] += *(const f32x4*)&red[((wave*16) + rf*2 + c)*256 + lane*4];
  }
  __syncthreads();
  if(wave < 2){
    #pragma unroll
    for(int rf=0;rf<8;rf++)
      #pragma unroll
      for(int c=0;c<2;c++)
        *(f32x4*)&red[((wave*16) + rf*2 + c)*256 + lane*4] = acc[rf][c];
  }
  __syncthreads();
  #pragma unroll
  for(int i=0;i<4;i++){
    int r = (tid>>3) + 32*i;
    int col0 = (tid&7)*4;
    int rf = r>>4, rr = r&15, q = rr>>2, g = rr&3;
    f32x4 v;
    #pragma unroll
    for(int j=0;j<4;j++){
      int col = col0+j; int c = col>>4, lo2 = col&15;
      int lane2 = q*16+lo2;
      v[j] = red[(rf*2 + c)*256 + lane2*4 + g]
           + red[(16 + rf*2 + c)*256 + lane2*4 + g];
    }
    *(f32x4*)(Cdst + (size_t)r*N + col0) = v;
  }
}

// ---- GRU row (phase B), lifted from k_gru ----
__device__ void gru_row(int b, int t, int dt, const float* z2p, const float* paramF,
                        const float* determ, float* deter, bf16* deterB, void* out, float* sm)
{
  int tid = threadIdx.x;
  float zz[12]; float s=0.f, s2=0.f;
  #pragma unroll
  for(int i=0;i<12;i++){
    int h = tid + 256*i;
    float acc = paramF[Pbg + h]
              + z2p[(size_t)b*GRUN_ + h]
              + z2p[(size_t)(B_ + b)*GRUN_ + h];
    zz[i]=acc; s+=acc; s2+=acc*acc;
  }
  block_reduce2(s, s2, sm);
  float mean = s/GRUN_, var = s2/GRUN_ - mean*mean;
  float rstd = rsqrtf(fmaxf(var,0.f) + 1e-5f);
  #pragma unroll
  for(int j=0;j<4;j++){
    int h0 = tid + 256*j;
    float lnr = (zz[j]   - mean)*rstd*paramF[Pgg+h0     ] + paramF[Pbng+h0     ];
    float lnc = (zz[j+4] - mean)*rstd*paramF[Pgg+h0+1024] + paramF[Pbng+h0+1024];
    float lnu = (zz[j+8] - mean)*rstd*paramF[Pgg+h0+2048] + paramF[Pbng+h0+2048];
    float reset = sigm_(lnr);
    float cand  = tanhf(reset*lnc);
    float upd   = sigm_(lnu - 1.f);          // UPDATE_BIAS
    float dn = upd*cand + (1.f-upd)*determ[b*DETER_+h0];
    deter[b*DETER_+h0]  = dn;
    deterB[b*DETER_+h0] = f2bf(dn);
    stout(out, dt, ((size_t)b*T_+t)*OUTW_ + 192 + h0, dn);
  }
}

// ---- tail row (phase D), lifted from k_tail; z3=2 parts, z5=4 parts ----
__device__ void tail_row(int b, int t, int dt, int enc,
                         const float* z3p, const float* z5p, const float* paramF,
                         const float* actF, const void* isf,
                         const float* deter, float* determ, bf16* A2,
                         void* out, const int* ens_ix, float* S)
{
  float* hs   = S;          // 1024
  float* xo   = S + 1024;   // 1024
  float* red  = S + 2048;   // 256
  float* dsO  = S + 2304;   // 128
  float* in44 = S + 2432;   // 48
  float* sm   = S + 2496;   // 8
  int tid = threadIdx.x;
  int idx = ens_ix[t];
  float z3v[4], z5v[4]; float s3=0.f,q3=0.f,s5=0.f,q5=0.f;
  #pragma unroll
  for(int i=0;i<4;i++){
    int h = tid + 256*i;
    float a3 = z3p[(size_t)b*HID_ + h] + z3p[(size_t)(B_ + b)*HID_ + h]
             + paramF[Pb3 + idx*HID_ + h];
    z3v[i]=a3; s3+=a3; q3+=a3*a3;
    float a5 = z5p[(size_t)b*HID_ + h] + z5p[(size_t)(B_ + b)*HID_ + h]
             + z5p[(size_t)(2*B_ + b)*HID_ + h] + z5p[(size_t)(3*B_ + b)*HID_ + h]
             + paramF[Pb5 + h];
    z5v[i]=a5; s5+=a5; q5+=a5*a5;
  }
  block_reduce2(s3, q3, sm);
  block_reduce2(s5, q5, sm);
  float m3=s3/HID_, v3=q3/HID_-m3*m3, r3=rsqrtf(fmaxf(v3,0.f)+1e-5f);
  float m5=s5/HID_, v5=q5/HID_-m5*m5, r5=rsqrtf(fmaxf(v5,0.f)+1e-5f);
  #pragma unroll
  for(int i=0;i<4;i++){
    int h = tid + 256*i;
    hs[h] = elu_((z3v[i]-m3)*r3*paramF[Pg3+idx*HID_+h] + paramF[Pbn3+idx*HID_+h]);
    xo[h] = elu_((z5v[i]-m5)*r5*paramF[Pg5+h] + paramF[Pbn5+h]);
  }
  __syncthreads();
  int j = tid & 63, cch = tid >> 6;
  {
    const float* W = paramF + PW4 + (size_t)idx*HID_*64;
    float a = 0.f;
    for(int k=cch*256; k<cch*256+256; k++) a += hs[k]*W[k*64 + j];
    red[tid] = a;
    __syncthreads();
    if(tid < 64) dsO[tid] = red[tid]+red[tid+64]+red[tid+128]+red[tid+192] + paramF[Pb4+idx*64+tid];
    __syncthreads();
    const float* W6f = paramF + PW6;
    a = 0.f;
    for(int k=cch*256; k<cch*256+256; k++) a += xo[k]*W6f[k*64 + j];
    red[tid] = a;
    __syncthreads();
    if(tid < 64) dsO[64+tid] = red[tid]+red[tid+64]+red[tid+128]+red[tid+192] + paramF[Pb6+tid];
    __syncthreads();
  }
  size_t ob = ((size_t)b*T_ + t)*OUTW_;
  if(tid < 32){
    float pm = dsO[tid];
    float ps = softplus_(dsO[32+tid]) + 0.1f;
    float om = dsO[64+tid];
    float os = softplus_(dsO[96+tid]) + 0.1f;
    stout(out, dt, ob+tid,      om);   // omean
    stout(out, dt, ob+32+tid,   os);   // ostd
    stout(out, dt, ob+64+tid,   om);   // post_stoch
    stout(out, dt, ob+96+tid,   pm);   // pmean
    stout(out, dt, ob+128+tid,  ps);   // pstd
    stout(out, dt, ob+160+tid,  pm);   // prior_stoch
  }
  // ---- step_in for t+1 (block-local stoch carry = dsO[64..95]) ----
  if(t+1 < T_){
    float m = maskv(isf, enc, b*T_ + (t+1));
    if(tid < 32)       in44[tid] = dsO[64+tid]*m;
    else if(tid < 44)  in44[tid] = actF[(size_t)(b*T_+(t+1))*ACT_ + (tid-32)]*m;
    __syncthreads();
    const float* W1f = paramF + PW1;
    float z[4]; float s=0.f, s2=0.f;
    #pragma unroll
    for(int i=0;i<4;i++){
      int h = tid + 256*i;
      float acc = paramF[Pb1 + h];
      for(int k=0;k<STOCH_+ACT_;k++) acc += in44[k]*W1f[k*HID_ + h];
      z[i]=acc; s+=acc; s2+=acc*acc;
    }
    block_reduce2(s, s2, sm);
    float mean = s/HID_, var = s2/HID_ - mean*mean;
    float rstd = rsqrtf(fmaxf(var,0.f) + 1e-5f);
    #pragma unroll
    for(int i=0;i<4;i++){
      int h = tid + 256*i;
      float xv = (z[i]-mean)*rstd*paramF[Pg1+h] + paramF[Pbn1+h];
      A2[(size_t)b*GRUK_ + h] = f2bf(elu_(xv));
      float dm = deter[b*DETER_+h]*m;
      determ[b*DETER_+h] = dm;
      A2[(size_t)b*GRUK_ + HID_ + h] = f2bf(dm);
    }
  }
}

// ---- persistent fused scan: all 64 steps, 4 phases/step, grid barriers ----
__global__ __launch_bounds__(256,1) void k_persist(
    bf16* A2, float* deter, float* determ, bf16* deterB,
    float* z2p, float* z3p, float* z5p,
    const bf16* WgT, const bf16* W3T, const bf16* W5T, const bf16* embB,
    const float* paramF, const float* actF, const void* isf,
    const int* dflag, const int* ens_ix, void* out, int* bar)
{
  __shared__ float S[8192];   // 32 KB: gemm reduce / tail scratch (disjoint slices)
  int bid = blockIdx.x;
  int sense = 0;
  int dt  = dflag[0];
  int enc = dflag[1];
  for(int t=0; t<T_; t++){
    // Phase A: z2 parts = A2[128,2048] @ WgT   (192 blocks: 96 ct x 2 K-parts)
    {
      int ct = bid % 96, part = bid / 96;
      gemm_tile(A2, nullptr, GRUK_, 0, 1<<30,
                WgT + (size_t)ct*32*GRUK_, GRUK_, GRUN_,
                part*1024, 1024,
                z2p + (size_t)part*B_*GRUN_ + ct*32, S);
    }
    gbar(bar, sense);
    // Phase B: GRU + LN over 3072 -> deter     (128 blocks)
    if(bid < B_)
      gru_row(bid, t, dt, z2p, paramF, determ, deter, deterB, out, S);
    gbar(bar, sense);
    // Phase C: z3 (2 K-parts) + z5 (4 K-parts) (64 + 128 = 192 blocks)
    if(bid < 64){
      int ct = bid & 31, part = bid >> 5;
      int idx = ens_ix[t];
      gemm_tile(deterB, nullptr, DETER_, 0, 1<<30,
                W3T + (size_t)idx*DETER_*HID_ + (size_t)ct*32*DETER_, DETER_, HID_,
                part*512, 512,
                z3p + (size_t)part*B_*HID_ + ct*32, S);
    } else {
      int b2 = bid - 64, ct = b2 & 31, part = b2 >> 5;
      gemm_tile(deterB, embB + (size_t)t*EMB_, DETER_, T_*EMB_, DETER_,
                W5T + (size_t)ct*32*OBSK_, OBSK_, HID_,
                part*640, 640,
                z5p + (size_t)part*B_*HID_ + ct*32, S);
    }
    gbar(bar, sense);
    // Phase D: heads + outputs + step_in(t+1)  (128 blocks)
    if(bid < B_)
      tail_row(bid, t, dt, enc, z3p, z5p, paramF, actF, isf,
               deter, determ, A2, out, ens_ix, S);
    gbar(bar, sense);   // also the A2/determ -> phase A barrier for t+1
  }
}

// ---- init: step_in for t=0 with zero carry state ----
__global__ __launch_bounds__(256) void k_init(
    const float* actF, const void* isf, const int* dflag,
    const float* paramF, float* determ, bf16* A2)
{
  __shared__ float in44[48];
  __shared__ float sm[8];
  int b = blockIdx.x, tid = threadIdx.x;
  float m = maskv(isf, dflag[1], b*T_);
  if(tid < 32)       in44[tid] = 0.f;
  else if(tid < 44)  in44[tid] = actF[(size_t)(b*T_)*ACT_ + (tid-32)]*m;
  __syncthreads();
  const float* W1f = paramF + PW1;
  float z[4]; float s=0.f, s2=0.f;
  #pragma unroll
  for(int i=0;i<4;i++){
    int h = tid + 256*i;
    float acc = paramF[Pb1 + h];
    for(int k=0;k<STOCH_+ACT_;k++) acc += in44[k]*W1f[k*HID_ + h];
    z[i]=acc; s+=acc; s2+=acc*acc;
  }
  block_reduce2(s, s2, sm);
  float mean = s/HID_, var = s2/HID_ - mean*mean;
  float rstd = rsqrtf(fmaxf(var,0.f) + 1e-5f);
  #pragma unroll
  for(int i=0;i<4;i++){
    int h = tid + 256*i;
    float xv = (z[i]-mean)*rstd*paramF[Pg1+h] + paramF[Pbn1+h];
    A2[(size_t)b*GRUK_ + h] = f2bf(elu_(xv));
    determ[b*DETER_+h] = 0.f;
    A2[(size_t)b*GRUK_ + HID_ + h] = f2bf(0.f);
  }
}

extern "C" void kernel_launch(void* const* d_in, const int* in_sizes, int n_in,
                              void* d_out, int out_size, void* d_ws, size_t ws_size,
                              hipStream_t stream)
{
  const void* embed  = d_in[0];
  const void* action = d_in[1];
  const void* isf    = d_in[2];
  const int*  ens_ix = (const int*)d_in[3];

  char* ws = (char*)d_ws;
  float* deter  = (float*)(ws + 0);            // 512 KB
  float* determ = (float*)(ws + 524288);       // 512 KB
  bf16*  A2     = (bf16*) (ws + 1048576);      // 512 KB
  bf16*  deterB = (bf16*) (ws + 1572864);      // 256 KB
  float* z2p    = (float*)(ws + 1835008);      // 3 MB   (2 parts x 128x3072 f32)
  float* z3p    = (float*)(ws + 4980736);      // 1 MB   (2 parts x 128x1024 f32)
  float* z5p    = (float*)(ws + 6029312);      // 2 MB   (4 parts x 128x1024 f32)
  bf16*  WgT    = (bf16*) (ws + 8126464);      // 12.6 MB
  bf16*  W3T    = (bf16*) (ws + 20709376);     // 10.5 MB
  bf16*  W5T    = (bf16*) (ws + 31195136);     // 5.2 MB
  float* paramF = (float*)(ws + 36438016);     // 1.88 MB
  bf16*  embB   = (bf16*) (ws + 38315520);     // 25.2 MB
  float* actF   = (float*)(ws + 63481344);     // 0.39 MB
  int*   dflag  = (int*)  (ws + 63874560);
  int*   bar    = (int*)  (ws + 63874816);     // barrier state, own cache line

  k_detect_dtype<<<1,256,0,stream>>>((const unsigned short*)embed, dflag, bar);
  k_detect_isf<<<1,256,0,stream>>>((const unsigned char*)isf, dflag);

  PDesc pd;
  const int srcidx[17] = {4,5,6,7, 9,10,11, 13,14,15, 17, 19,20,21, 23, 16, 22};
  const int sizes[17]  = {45056,1024,1024,1024, 3072,3072,3072, 5120,5120,5120,
                          320, 1024,1024,1024, 64, 327680, 65536};
  int cum = 0;
  for(int i=0;i<17;i++){ pd.src[i] = d_in[srcidx[i]]; pd.cum[i] = cum; cum += sizes[i]; }
  pd.cum[17] = cum;  // 469376
  k_params<<<(PTOT+255)/256, 256, 0, stream>>>(pd, paramF, dflag);

  k_cvt_bf<<<(B_*T_*EMB_)/1024, 256, 0, stream>>>(embed, embB, B_*T_*EMB_, dflag);
  k_cvt_f<<<(B_*T_*ACT_+1023)/1024, 256, 0, stream>>>(action, actF, B_*T_*ACT_, dflag);

  k_transpose<<<dim3((GRUK_/64)*(GRUN_/64),1), 256, 0, stream>>>(d_in[8],  WgT, GRUK_, GRUN_, dflag);
  k_transpose<<<dim3((DETER_/64)*(HID_/64),5), 256, 0, stream>>>(d_in[12], W3T, DETER_, HID_, dflag);
  k_transpose<<<dim3((OBSK_/64)*(HID_/64),1), 256, 0, stream>>>(d_in[18], W5T, OBSK_, HID_, dflag);

  k_init<<<B_,256,0,stream>>>(actF, isf, dflag, paramF, determ, A2);

  // one persistent kernel replaces 256 per-step launches
  k_persist<<<GRID_,256,0,stream>>>(A2, deter, determ, deterB, z2p, z3p, z5p,
                                    WgT, W3T, W5T, embB, paramF, actF, isf,
                                    dflag, ens_ix, d_out, bar);
}

// Round 2
// 17453.273 us; speedup vs baseline: 1.0174x; 1.0174x over previous
//
#include <hip/hip_runtime.h>
#include <hip/hip_bf16.h>
#include <math.h>

using bf16 = __hip_bfloat16;
using short8 = __attribute__((ext_vector_type(8))) short;
using f32x4  = __attribute__((ext_vector_type(4))) float;

#define B_     128
#define T_     64
#define EMB_   1536
#define ACT_   12
#define STOCH_ 32
#define DETER_ 1024
#define HID_   1024
#define GRUN_  3072
#define GRUK_  2048
#define OBSK_  2560
#define OUTW_  1216   // 6*STOCH + DETER

// canonical f32 param block offsets (floats)
#define PW1   0
#define Pb1   45056
#define Pg1   46080
#define Pbn1  47104
#define Pbg   48128
#define Pgg   51200
#define Pbng  54272
#define Pb3   57344
#define Pg3   62464
#define Pbn3  67584
#define Pb4   72704
#define Pb5   73024
#define Pg5   74048
#define Pbn5  75072
#define Pb6   76096
#define PW4   76160
#define PW6   403840
#define PTOT  469376

#define NBLK  192   // persistent blocks: 1/CU co-resident (<=256 CUs)

__device__ inline float bf2f(bf16 v){ return __bfloat162float(v); }
__device__ inline bf16  f2bf(float v){ return __float2bfloat16(v); }
__device__ inline float elu_(float x){ return x > 0.f ? x : expm1f(x); }
__device__ inline float sigm_(float x){ return 1.f/(1.f+expf(-x)); }
__device__ inline float softplus_(float x){ return fmaxf(x,0.f) + log1pf(expf(-fabsf(x))); }
__device__ inline void stout(void* out, int dt, size_t i, float v){
  if(dt) ((bf16*)out)[i] = f2bf(v); else ((float*)out)[i] = v;
}
__device__ inline float maskv(const void* isf, int enc, int idx){
  float fv;
  if(enc==0)      fv = (float)((const int*)isf)[idx];
  else if(enc==1) fv = (float)((const unsigned char*)isf)[idx];
  else if(enc==2) fv = bf2f(((const bf16*)isf)[idx]);
  else            fv = ((const float*)isf)[idx];
  return (fv != 0.f) ? 0.f : 1.f;
}

// ---- agent-scope (sc1) accessors: bypass stale L2, no cache-wide fences ----
__device__ inline float aldf(const float* p){
  return __hip_atomic_load((float*)p, __ATOMIC_RELAXED, __HIP_MEMORY_SCOPE_AGENT);
}
__device__ inline unsigned aldu(const unsigned* p){
  return __hip_atomic_load((unsigned*)p, __ATOMIC_RELAXED, __HIP_MEMORY_SCOPE_AGENT);
}
__device__ inline void astf(float* p, float v){
  __hip_atomic_store(p, v, __ATOMIC_RELAXED, __HIP_MEMORY_SCOPE_AGENT);
}
__device__ inline void astu(unsigned* p, unsigned v){
  __hip_atomic_store(p, v, __ATOMIC_RELAXED, __HIP_MEMORY_SCOPE_AGENT);
}

// 256-thread block reduction of two values (sum, sumsq)
__device__ inline void block_reduce2(float& a, float& b, float* sm){
  __syncthreads();
  for(int off=32; off>0; off>>=1){
    a += __shfl_down(a, off);
    b += __shfl_down(b, off);
  }
  int w = threadIdx.x >> 6;
  if((threadIdx.x & 63) == 0){ sm[2*w] = a; sm[2*w+1] = b; }
  __syncthreads();
  a = sm[0]+sm[2]+sm[4]+sm[6];
  b = sm[1]+sm[3]+sm[5]+sm[7];
}

// ---- zero-contention device barrier ----
// arr: 192 slots x 16 ints (64B apart). rel: single release flag.
// arrive: per-block slot store (no RMW). block 0 aggregates (192 threads
// poll one slot each), then one release store. waiters poll release with
// s_sleep backoff. No buffer_wbl2/inv anywhere -> weight L2 stays hot.
// Data visibility: cross-block data uses sc1 ops; __syncthreads drains
// vmcnt before the arrival store, so data is at the coherence point first.
__device__ inline void gbar2(int* arr, int* rel, int epoch, int bid){
  __syncthreads();
  __atomic_signal_fence(__ATOMIC_SEQ_CST);
  if(threadIdx.x == 0)
    __hip_atomic_store(&arr[bid*16], epoch, __ATOMIC_RELAXED, __HIP_MEMORY_SCOPE_AGENT);
  if(bid == 0){
    if(threadIdx.x < NBLK){
      int it = 0;
      while(__hip_atomic_load(&arr[threadIdx.x*16], __ATOMIC_RELAXED, __HIP_MEMORY_SCOPE_AGENT) < epoch){
        __builtin_amdgcn_s_sleep(1);
        if(++it > (1<<16)) break;   // safety valve: fail-fast, no hang
      }
    }
    __syncthreads();
    if(threadIdx.x == 0)
      __hip_atomic_store(rel, epoch, __ATOMIC_RELAXED, __HIP_MEMORY_SCOPE_AGENT);
  } else {
    if(threadIdx.x == 0){
      int it = 0;
      while(__hip_atomic_load(rel, __ATOMIC_RELAXED, __HIP_MEMORY_SCOPE_AGENT) < epoch){
        __builtin_amdgcn_s_sleep(8);
        if(++it > (1<<16)) break;
      }
    }
    __syncthreads();
  }
  __atomic_signal_fence(__ATOMIC_SEQ_CST);
}

// ---- detect float dtype from embed buffer: dflag[0] = 1 if bf16, 0 if f32 ----
__global__ void k_detect_dtype(const unsigned short* emb, int* dflag){
  __shared__ int cnt;
  if(threadIdx.x==0) cnt = 0;
  __syncthreads();
  int c = 0;
  for(int i=threadIdx.x; i<2048; i+=256){
    unsigned short u = emb[2*i];
    int exp8 = (u >> 7) & 0xFF;
    if(exp8 > 140) c++;
  }
  atomicAdd(&cnt, c);
  __syncthreads();
  if(threadIdx.x==0) dflag[0] = (cnt < 100) ? 1 : 0;
}

// ---- detect is_first encoding: dflag[1] = 0 int32, 1 uint8, 2 bf16, 3 f32 ----
__global__ void k_detect_isf(const unsigned char* isf, int* dflag){
  __shared__ int f_bf, f_f32, f_u8;
  if(threadIdx.x==0){ f_bf=0; f_f32=0; f_u8=0; }
  __syncthreads();
  for(int i=threadIdx.x; i<B_*T_; i+=256){
    unsigned char c = isf[i];
    if(c == 0x3F){
      if((i & 3) == 1) atomicOr(&f_bf, 1);
      else if((i & 3) == 3) atomicOr(&f_f32, 1);
    }
    if(c == 1 && (i & 3) != 0) atomicOr(&f_u8, 1);
  }
  __syncthreads();
  if(threadIdx.x==0)
    dflag[1] = f_bf ? 2 : (f_f32 ? 3 : (f_u8 ? 1 : 0));
}

// ---- batched param conversion -> canonical f32 block ----
struct PDesc { const void* src[17]; int cum[18]; };
__global__ __launch_bounds__(256) void k_params(PDesc pd, float* dst, const int* dflag){
  int g = blockIdx.x*256 + threadIdx.x;
  if(g >= PTOT) return;
  int dt = dflag[0];
  int s = 0;
  while(g >= pd.cum[s+1]) s++;
  int off = g - pd.cum[s];
  dst[g] = dt ? bf2f(((const bf16*)pd.src[s])[off]) : ((const float*)pd.src[s])[off];
}

__global__ void k_cvt_bf(const void* src, bf16* dst, int n, const int* dflag){
  int dt = dflag[0];
  int i0 = (blockIdx.x*256 + threadIdx.x)*4;
  #pragma unroll
  for(int k=0;k<4;k++){
    int i = i0+k;
    if(i < n) dst[i] = dt ? ((const bf16*)src)[i] : f2bf(((const float*)src)[i]);
  }
}

__global__ void k_cvt_f(const void* src, float* dst, int n, const int* dflag){
  int dt = dflag[0];
  int i0 = (blockIdx.x*256 + threadIdx.x)*4;
  #pragma unroll
  for(int k=0;k<4;k++){
    int i = i0+k;
    if(i < n) dst[i] = dt ? bf2f(((const bf16*)src)[i]) : ((const float*)src)[i];
  }
}

// ---- tiled transpose: src[K][N] -> dst[N][K] (bf16 canonical), head = blockIdx.y ----
__global__ __launch_bounds__(256) void k_transpose(const void* src, bf16* dst, int K, int N, const int* dflag){
  __shared__ unsigned short t[64][72];
  int dt = dflag[0];
  int tilesN = N/64;
  int tk = blockIdx.x / tilesN, tn = blockIdx.x % tilesN;
  size_t hoff = (size_t)blockIdx.y * K * N;
  unsigned short* d = (unsigned short*)dst + hoff;
  int tx = threadIdx.x & 63, ty0 = threadIdx.x >> 6;
  int k0 = tk*64, n0 = tn*64;
  #pragma unroll
  for(int i=0;i<16;i++){
    int ty = ty0*16+i;
    size_t off = hoff + (size_t)(k0+ty)*N + n0+tx;
    unsigned short v;
    if(dt) v = ((const unsigned short*)src)[off];
    else { bf16 b = f2bf(((const float*)src)[off]); v = *(unsigned short*)&b; }
    t[ty][tx] = v;
  }
  __syncthreads();
  #pragma unroll
  for(int i=0;i<16;i++){ int ty = ty0*16+i; d[(size_t)(n0+ty)*K + k0+tx] = t[tx][ty]; }
}

// ---- MFMA GEMM tile: 128x32 output, K split over 4 waves, LDS reduce ----
// SCA: A0 loads via agent(sc1) dword atomics (cross-block producer data).
// SCC: C stores via agent(sc1) dword atomics. A1 path is always normal
// (read-only embB). kf<split is wave-uniform in every caller.
template<bool SCA, bool SCC>
__device__ void gemm_tile(const bf16* A0, const bf16* A1, int s0, int s1, int split,
                          const bf16* BT, int ldb, int N, int k0, int kc,
                          float* Cdst, float* red)
{
  int tid = threadIdx.x;
  int wave = tid >> 6, lane = tid & 63;
  int quad = lane >> 4, lo = lane & 15;
  int kw0 = k0 + wave*(kc>>2), kw1 = kw0 + (kc>>2);
  f32x4 acc[8][2];
  #pragma unroll
  for(int rf=0;rf<8;rf++){ acc[rf][0]=(f32x4)0.f; acc[rf][1]=(f32x4)0.f; }
  for(int kk=kw0; kk<kw1; kk+=32){
    int kf = kk + quad*8;
    short8 af[8], bfg[2];
    if(kf < split){
      #pragma unroll
      for(int rf=0;rf<8;rf++){
        const void* p = (const void*)(A0 + (size_t)(16*rf+lo)*s0 + kf);
        if(SCA){
          union { unsigned u[4]; short8 s8; } v;
          const unsigned* q = (const unsigned*)p;
          #pragma unroll
          for(int w=0;w<4;w++) v.u[w] = aldu(q+w);
          af[rf] = v.s8;
        } else {
          af[rf] = *(const short8*)p;
        }
      }
    } else {
      #pragma unroll
      for(int rf=0;rf<8;rf++)
        af[rf] = *(const short8*)(const void*)(A1 + (size_t)(16*rf+lo)*s1 + (kf-split));
    }
    #pragma unroll
    for(int c=0;c<2;c++)
      bfg[c] = *(const short8*)(const void*)(BT + (size_t)(16*c+lo)*ldb + kf);
    #pragma unroll
    for(int rf=0;rf<8;rf++){
      acc[rf][0] = __builtin_amdgcn_mfma_f32_16x16x32_bf16(af[rf], bfg[0], acc[rf][0], 0,0,0);
      acc[rf][1] = __builtin_amdgcn_mfma_f32_16x16x32_bf16(af[rf], bfg[1], acc[rf][1], 0,0,0);
    }
  }
  // cross-wave reduce: waves 2,3 dump -> waves 0,1 add -> waves 0,1 dump -> all sum pairs
  if(wave >= 2){
    #pragma unroll
    for(int rf=0;rf<8;rf++)
      #pragma unroll
      for(int c=0;c<2;c++)
        *(f32x4*)&red[(((wave-2)*16) + rf*2 + c)*256 + lane*4] = acc[rf][c];
  }
  __syncthreads();
  if(wave < 2){
    #pragma unroll
    for(int rf=0;rf<8;rf++)
      #pragma unroll
      for(int c=0;c<2;c++)
        acc[rf][c] += *(const f32x4*)&red[((wave*16) + rf*2 + c)*256 + lane*4];
  }
  __syncthreads();
  if(wave < 2){
    #pragma unroll
    for(int rf=0;rf<8;rf++)
      #pragma unroll
      for(int c=0;c<2;c++)
        *(f32x4*)&red[((wave*16) + rf*2 + c)*256 + lane*4] = acc[rf][c];
  }
  __syncthreads();
  #pragma unroll
  for(int i=0;i<4;i++){
    int r = (tid>>3) + 32*i;
    int col0 = (tid&7)*4;
    int rf = r>>4, rr = r&15, q = rr>>2, g = rr&3;
    f32x4 v;
    #pragma unroll
    for(int j=0;j<4;j++){
      int col = col0+j; int c = col>>4, lo2 = col&15;
      int lane2 = q*16+lo2;
      v[j] = red[(rf*2 + c)*256 + lane2*4 + g]
           + red[(16 + rf*2 + c)*256 + lane2*4 + g];
    }
    float* pc = Cdst + (size_t)r*N + col0;
    if(SCC){
      #pragma unroll
      for(int j=0;j<4;j++) astf(pc+j, v[j]);
    } else {
      *(f32x4*)pc = v;
    }
  }
}

// ---- GRU row (phase B) ----
__device__ void gru_row(int b, int t, int dt, const float* z2p, const float* paramF,
                        const float* determ, float* deter, bf16* deterB, void* out, float* S)
{
  float* sm = S;                               // 8 floats
  unsigned short* dnr = (unsigned short*)(S+16);  // 1024 ushorts
  int tid = threadIdx.x;
  float zz[12]; float s=0.f, s2=0.f;
  #pragma unroll
  for(int i=0;i<12;i++){
    int h = tid + 256*i;
    float acc = paramF[Pbg + h]
              + aldf(z2p + (size_t)b*GRUN_ + h)
              + aldf(z2p + (size_t)(B_ + b)*GRUN_ + h);
    zz[i]=acc; s+=acc; s2+=acc*acc;
  }
  block_reduce2(s, s2, sm);
  float mean = s/GRUN_, var = s2/GRUN_ - mean*mean;
  float rstd = rsqrtf(fmaxf(var,0.f) + 1e-5f);
  #pragma unroll
  for(int j=0;j<4;j++){
    int h0 = tid + 256*j;
    float lnr = (zz[j]   - mean)*rstd*paramF[Pgg+h0     ] + paramF[Pbng+h0     ];
    float lnc = (zz[j+4] - mean)*rstd*paramF[Pgg+h0+1024] + paramF[Pbng+h0+1024];
    float lnu = (zz[j+8] - mean)*rstd*paramF[Pgg+h0+2048] + paramF[Pbng+h0+2048];
    float reset = sigm_(lnr);
    float cand  = tanhf(reset*lnc);
    float upd   = sigm_(lnu - 1.f);          // UPDATE_BIAS
    float dn = upd*cand + (1.f-upd)*determ[b*DETER_+h0];
    deter[b*DETER_+h0] = dn;                 // same-block consumer (tail)
    bf16 bv = f2bf(dn);
    dnr[h0] = *(unsigned short*)&bv;
    stout(out, dt, ((size_t)b*T_+t)*OUTW_ + 192 + h0, dn);
  }
  __syncthreads();
  // publish deterB (cross-block) as sc1 dwords from LDS staging
  unsigned* db = (unsigned*)(deterB + (size_t)b*DETER_);
  const unsigned* sp = (const unsigned*)dnr;
  #pragma unroll
  for(int i=0;i<2;i++) astu(db + tid + 256*i, sp[tid + 256*i]);
}

// ---- tail row (phase D): heads + outputs + step_in(t+1) ----
__device__ void tail_row(int b, int t, int dt, int enc,
                         const float* z3p, const float* z5p, const float* paramF,
                         const float* actF, const void* isf,
                         const float* deter, float* determ, bf16* A2,
                         void* out, const int* ens_ix, float* S)
{
  float* hs   = S;          // 1024
  float* xo   = S + 1024;   // 1024
  float* red  = S + 2048;   // 256
  float* dsO  = S + 2304;   // 128
  float* in44 = S + 2432;   // 48
  float* sm   = S + 2496;   // 8
  unsigned short* a2s = (unsigned short*)(S + 2560);  // 2048 ushorts
  int tid = threadIdx.x;
  int idx = ens_ix[t];
  float z3v[4], z5v[4]; float s3=0.f,q3=0.f,s5=0.f,q5=0.f;
  #pragma unroll
  for(int i=0;i<4;i++){
    int h = tid + 256*i;
    float a3 = aldf(z3p + (size_t)b*HID_ + h) + aldf(z3p + (size_t)(B_ + b)*HID_ + h)
             + paramF[Pb3 + idx*HID_ + h];
    z3v[i]=a3; s3+=a3; q3+=a3*a3;
    float a5 = aldf(z5p + (size_t)b*HID_ + h) + aldf(z5p + (size_t)(B_ + b)*HID_ + h)
             + aldf(z5p + (size_t)(2*B_ + b)*HID_ + h) + aldf(z5p + (size_t)(3*B_ + b)*HID_ + h)
             + paramF[Pb5 + h];
    z5v[i]=a5; s5+=a5; q5+=a5*a5;
  }
  block_reduce2(s3, q3, sm);
  block_reduce2(s5, q5, sm);
  float m3=s3/HID_, v3=q3/HID_-m3*m3, r3=rsqrtf(fmaxf(v3,0.f)+1e-5f);
  float m5=s5/HID_, v5=q5/HID_-m5*m5, r5=rsqrtf(fmaxf(v5,0.f)+1e-5f);
  #pragma unroll
  for(int i=0;i<4;i++){
    int h = tid + 256*i;
    hs[h] = elu_((z3v[i]-m3)*r3*paramF[Pg3+idx*HID_+h] + paramF[Pbn3+idx*HID_+h]);
    xo[h] = elu_((z5v[i]-m5)*r5*paramF[Pg5+h] + paramF[Pbn5+h]);
  }
  __syncthreads();
  int j = tid & 63, cch = tid >> 6;
  {
    const float* W = paramF + PW4 + (size_t)idx*HID_*64;
    float a = 0.f;
    for(int k=cch*256; k<cch*256+256; k++) a += hs[k]*W[k*64 + j];
    red[tid] = a;
    __syncthreads();
    if(tid < 64) dsO[tid] = red[tid]+red[tid+64]+red[tid+128]+red[tid+192] + paramF[Pb4+idx*64+tid];
    __syncthreads();
    const float* W6f = paramF + PW6;
    a = 0.f;
    for(int k=cch*256; k<cch*256+256; k++) a += xo[k]*W6f[k*64 + j];
    red[tid] = a;
    __syncthreads();
    if(tid < 64) dsO[64+tid] = red[tid]+red[tid+64]+red[tid+128]+red[tid+192] + paramF[Pb6+tid];
    __syncthreads();
  }
  size_t ob = ((size_t)b*T_ + t)*OUTW_;
  if(tid < 32){
    float pm = dsO[tid];
    float ps = softplus_(dsO[32+tid]) + 0.1f;
    float om = dsO[64+tid];
    float os = softplus_(dsO[96+tid]) + 0.1f;
    stout(out, dt, ob+tid,      om);   // omean
    stout(out, dt, ob+32+tid,   os);   // ostd
    stout(out, dt, ob+64+tid,   om);   // post_stoch
    stout(out, dt, ob+96+tid,   pm);   // pmean
    stout(out, dt, ob+128+tid,  ps);   // pstd
    stout(out, dt, ob+160+tid,  pm);   // prior_stoch
  }
  // ---- step_in for t+1 (block-local stoch carry = dsO[64..95]) ----
  if(t+1 < T_){
    float m = maskv(isf, enc, b*T_ + (t+1));
    if(tid < 32)       in44[tid] = dsO[64+tid]*m;
    else if(tid < 44)  in44[tid] = actF[(size_t)(b*T_+(t+1))*ACT_ + (tid-32)]*m;
    __syncthreads();
    const float* W1f = paramF + PW1;
    float z[4]; float s=0.f, s2=0.f;
    #pragma unroll
    for(int i=0;i<4;i++){
      int h = tid + 256*i;
      float acc = paramF[Pb1 + h];
      for(int k=0;k<STOCH_+ACT_;k++) acc += in44[k]*W1f[k*HID_ + h];
      z[i]=acc; s+=acc; s2+=acc*acc;
    }
    block_reduce2(s, s2, sm);
    float mean = s/HID_, var = s2/HID_ - mean*mean;
    float rstd = rsqrtf(fmaxf(var,0.f) + 1e-5f);
    #pragma unroll
    for(int i=0;i<4;i++){
      int h = tid + 256*i;
      float xv = (z[i]-mean)*rstd*paramF[Pg1+h] + paramF[Pbn1+h];
      bf16 xb = f2bf(elu_(xv));
      a2s[h] = *(unsigned short*)&xb;
      float dm = deter[b*DETER_+h]*m;
      determ[b*DETER_+h] = dm;               // same-block consumer (gru)
      bf16 db = f2bf(dm);
      a2s[1024+h] = *(unsigned short*)&db;
    }
    __syncthreads();
    // publish A2 row (cross-block) as sc1 dwords from LDS staging
    unsigned* ab = (unsigned*)(A2 + (size_t)b*GRUK_);
    const unsigned* sp = (const unsigned*)a2s;
    #pragma unroll
    for(int i=0;i<4;i++) astu(ab + tid + 256*i, sp[tid + 256*i]);
  }
}

// ---- persistent fused scan: 64 steps x 4 phases, slot-barrier synced ----
__global__ __launch_bounds__(256,1) void k_persist(
    bf16* A2, float* deter, float* determ, bf16* deterB,
    float* z2p, float* z3p, float* z5p,
    const bf16* WgT, const bf16* W3T, const bf16* W5T, const bf16* embB,
    const float* paramF, const float* actF, const void* isf,
    const int* dflag, const int* ens_ix, void* out, int* bar)
{
  __shared__ float S[8192];   // 32 KB scratch (disjoint per-phase slices)
  int bid = blockIdx.x;
  int ep = 0;
  int dt  = dflag[0];
  int enc = dflag[1];
  int* arr = bar;
  int* rel = bar + 4096;
  for(int t=0; t<T_; t++){
    // Phase A (192 blocks): z2 parts = A2[128,2048] @ WgT  (96 ct x 2 K-parts)
    {
      int ct = bid % 96, part = bid / 96;
      gemm_tile<true,true>(A2, nullptr, GRUK_, 0, 1<<30,
                WgT + (size_t)ct*32*GRUK_, GRUK_, GRUN_,
                part*1024, 1024,
                z2p + (size_t)part*B_*GRUN_ + ct*32, S);
    }
    gbar2(arr, rel, ++ep, bid);
    // Phase B: gru (128 blocks) || z5-emb partials (64 blocks, read-only inputs)
    if(bid < B_){
      gru_row(bid, t, dt, z2p, paramF, determ, deter, deterB, out, S);
    } else {
      int b2 = bid - B_;            // 0..63
      int ct = b2 & 31, part = b2 >> 5;   // part 0..1, K=768 each
      gemm_tile<false,true>(nullptr, embB + (size_t)t*EMB_, 0, T_*EMB_, 1024,
                W5T + (size_t)ct*32*OBSK_, OBSK_, HID_,
                1024 + part*768, 768,
                z5p + (size_t)(2+part)*B_*HID_ + ct*32, S);
    }
    gbar2(arr, rel, ++ep, bid);
    // Phase C (128 blocks): z3 (2 K-parts) + z5-deter (2 K-parts), K=512 each
    if(bid < 64){
      int ct = bid & 31, part = bid >> 5;
      int idx = ens_ix[t];
      gemm_tile<true,true>(deterB, nullptr, DETER_, 0, 1<<30,
                W3T + (size_t)idx*DETER_*HID_ + (size_t)ct*32*DETER_, DETER_, HID_,
                part*512, 512,
                z3p + (size_t)part*B_*HID_ + ct*32, S);
    } else if(bid < 128){
      int b2 = bid - 64; int ct = b2 & 31, part = b2 >> 5;
      gemm_tile<true,true>(deterB, nullptr, DETER_, 0, 1<<30,
                W5T + (size_t)ct*32*OBSK_, OBSK_, HID_,
                part*512, 512,
                z5p + (size_t)part*B_*HID_ + ct*32, S);
    }
    gbar2(arr, rel, ++ep, bid);
    // Phase D (128 blocks): heads + outputs + step_in(t+1)
    if(bid < B_)
      tail_row(bid, t, dt, enc, z3p, z5p, paramF, actF, isf,
               deter, determ, A2, out, ens_ix, S);
    gbar2(arr, rel, ++ep, bid);   // also A2/determ -> phase A of t+1
  }
}

// ---- init: step_in for t=0 with zero carry state; block 0 zeroes barrier ----
__global__ __launch_bounds__(256) void k_init(
    const float* actF, const void* isf, const int* dflag,
    const float* paramF, float* determ, bf16* A2, int* bar)
{
  __shared__ float in44[48];
  __shared__ float sm[8];
  int b = blockIdx.x, tid = threadIdx.x;
  if(b == 0){
    for(int i=tid; i<4608; i+=256) bar[i] = 0;
  }
  float m = maskv(isf, dflag[1], b*T_);
  if(tid < 32)       in44[tid] = 0.f;
  else if(tid < 44)  in44[tid] = actF[(size_t)(b*T_)*ACT_ + (tid-32)]*m;
  __syncthreads();
  const float* W1f = paramF + PW1;
  float z[4]; float s=0.f, s2=0.f;
  #pragma unroll
  for(int i=0;i<4;i++){
    int h = tid + 256*i;
    float acc = paramF[Pb1 + h];
    for(int k=0;k<STOCH_+ACT_;k++) acc += in44[k]*W1f[k*HID_ + h];
    z[i]=acc; s+=acc; s2+=acc*acc;
  }
  block_reduce2(s, s2, sm);
  float mean = s/HID_, var = s2/HID_ - mean*mean;
  float rstd = rsqrtf(fmaxf(var,0.f) + 1e-5f);
  #pragma unroll
  for(int i=0;i<4;i++){
    int h = tid + 256*i;
    float xv = (z[i]-mean)*rstd*paramF[Pg1+h] + paramF[Pbn1+h];
    A2[(size_t)b*GRUK_ + h] = f2bf(elu_(xv));
    determ[b*DETER_+h] = 0.f;
    A2[(size_t)b*GRUK_ + HID_ + h] = f2bf(0.f);
  }
}

extern "C" void kernel_launch(void* const* d_in, const int* in_sizes, int n_in,
                              void* d_out, int out_size, void* d_ws, size_t ws_size,
                              hipStream_t stream)
{
  const void* embed  = d_in[0];
  const void* action = d_in[1];
  const void* isf    = d_in[2];
  const int*  ens_ix = (const int*)d_in[3];

  char* ws = (char*)d_ws;
  float* deter  = (float*)(ws + 0);            // 512 KB
  float* determ = (float*)(ws + 524288);       // 512 KB
  bf16*  A2     = (bf16*) (ws + 1048576);      // 512 KB
  bf16*  deterB = (bf16*) (ws + 1572864);      // 256 KB
  float* z2p    = (float*)(ws + 1835008);      // 3 MB   (2 parts x 128x3072 f32)
  float* z3p    = (float*)(ws + 4980736);      // 1 MB   (2 parts x 128x1024 f32)
  float* z5p    = (float*)(ws + 6029312);      // 2 MB   (4 slots: 2 deter + 2 emb)
  bf16*  WgT    = (bf16*) (ws + 8126464);      // 12.6 MB
  bf16*  W3T    = (bf16*) (ws + 20709376);     // 10.5 MB
  bf16*  W5T    = (bf16*) (ws + 31195136);     // 5.2 MB
  float* paramF = (float*)(ws + 36438016);     // 1.88 MB
  bf16*  embB   = (bf16*) (ws + 38315520);     // 25.2 MB
  float* actF   = (float*)(ws + 63481344);     // 0.39 MB
  int*   dflag  = (int*)  (ws + 63874560);
  int*   bar    = (int*)  (ws + 63875072);     // 4608 ints: 192 slots + release

  k_detect_dtype<<<1,256,0,stream>>>((const unsigned short*)embed, dflag);
  k_detect_isf<<<1,256,0,stream>>>((const unsigned char*)isf, dflag);

  PDesc pd;
  const int srcidx[17] = {4,5,6,7, 9,10,11, 13,14,15, 17, 19,20,21, 23, 16, 22};
  const int sizes[17]  = {45056,1024,1024,1024, 3072,3072,3072, 5120,5120,5120,
                          320, 1024,1024,1024, 64, 327680, 65536};
  int cum = 0;
  for(int i=0;i<17;i++){ pd.src[i] = d_in[srcidx[i]]; pd.cum[i] = cum; cum += sizes[i]; }
  pd.cum[17] = cum;  // 469376
  k_params<<<(PTOT+255)/256, 256, 0, stream>>>(pd, paramF, dflag);

  k_cvt_bf<<<(B_*T_*EMB_)/1024, 256, 0, stream>>>(embed, embB, B_*T_*EMB_, dflag);
  k_cvt_f<<<(B_*T_*ACT_+1023)/1024, 256, 0, stream>>>(action, actF, B_*T_*ACT_, dflag);

  k_transpose<<<dim3((GRUK_/64)*(GRUN_/64),1), 256, 0, stream>>>(d_in[8],  WgT, GRUK_, GRUN_, dflag);
  k_transpose<<<dim3((DETER_/64)*(HID_/64),5), 256, 0, stream>>>(d_in[12], W3T, DETER_, HID_, dflag);
  k_transpose<<<dim3((OBSK_/64)*(HID_/64),1), 256, 0, stream>>>(d_in[18], W5T, OBSK_, HID_, dflag);

  k_init<<<B_,256,0,stream>>>(actF, isf, dflag, paramF, determ, A2, bar);

  // one persistent kernel replaces 256 per-step launches
  k_persist<<<NBLK,256,0,stream>>>(A2, deter, determ, deterB, z2p, z3p, z5p,
                                   WgT, W3T, W5T, embB, paramF, actF, isf,
                                   dflag, ens_ix, d_out, bar);
}

// Round 3
// 12756.143 us; speedup vs baseline: 1.3920x; 1.3682x over previous
//
#include <hip/hip_runtime.h>
#include <hip/hip_bf16.h>
#include <math.h>

using bf16 = __hip_bfloat16;
using short8 = __attribute__((ext_vector_type(8))) short;
using f32x4  = __attribute__((ext_vector_type(4))) float;

#define B_     128
#define T_     64
#define EMB_   1536
#define ACT_   12
#define STOCH_ 32
#define DETER_ 1024
#define HID_   1024
#define GRUN_  3072
#define GRUK_  2048
#define OBSK_  2560
#define OUTW_  1216   // 6*STOCH + DETER

// canonical f32 param block offsets (floats)
#define PW1   0
#define Pb1   45056
#define Pg1   46080
#define Pbn1  47104
#define Pbg   48128
#define Pgg   51200
#define Pbng  54272
#define Pb3   57344
#define Pg3   62464
#define Pbn3  67584
#define Pb4   72704
#define Pb5   73024
#define Pg5   74048
#define Pbn5  75072
#define Pb6   76096
#define PW4   76160
#define PW6   403840
#define PTOT  469376

#define NBLK  512      // persistent blocks, 2/CU co-resident via launch_bounds(256,2)

// bar[] layout (ints)
#define C_ARR   0        // 512 x 16 arrival slots (one-time global barrier)
#define C_REL   8192     // one-time release flag
#define C_CNT   8208     // 16 per-XCD registration counters
#define C_XBAR  8240     // 8 x 32: per-XCD {counter, pad..., release, pad...}
#define BAR_INTS 16384

// per-XCD scratch layout (bytes)
#define XSZ     655360
#define XO_Z2   0         // [16][3072] f32  192K
#define XO_Z3   196608    // [16][1024] f32   64K
#define XO_Z5   262144    // [16][1024] f32   64K
#define XO_Z5E  327680    // [16][1024] f32   64K
#define XO_DET  393216    // [16][1024] f32   64K  deter   (owner-block only)
#define XO_DETM 458752    // [16][1024] f32   64K  determ  (owner-block only)
#define XO_DETB 524288    // [16][1024] bf16  32K  published
#define XO_A2   557056    // [16][2048] bf16  64K  published

__device__ inline float bf2f(bf16 v){ return __bfloat162float(v); }
__device__ inline bf16  f2bf(float v){ return __float2bfloat16(v); }
__device__ inline float elu_(float x){ return x > 0.f ? x : expm1f(x); }
__device__ inline float sigm_(float x){ return 1.f/(1.f+expf(-x)); }
__device__ inline float softplus_(float x){ return fmaxf(x,0.f) + log1pf(expf(-fabsf(x))); }
__device__ inline void stout(void* out, int dt, size_t i, float v){
  if(dt) ((bf16*)out)[i] = f2bf(v); else ((float*)out)[i] = v;
}
__device__ inline float maskv(const void* isf, int enc, int idx){
  float fv;
  if(enc==0)      fv = (float)((const int*)isf)[idx];
  else if(enc==1) fv = (float)((const unsigned char*)isf)[idx];
  else if(enc==2) fv = bf2f(((const bf16*)isf)[idx]);
  else            fv = ((const float*)isf)[idx];
  return (fv != 0.f) ? 0.f : 1.f;
}

// ---- sc0 (L1-bypass, L2-coherent) bundled loads for intra-XCD peer data ----
__device__ inline void ld16_sc0(const void* p, short8* o){
  asm volatile(
    "global_load_dwordx4 %0, %16, off sc0\n\t"
    "global_load_dwordx4 %1, %16, off offset:64 sc0\n\t"
    "global_load_dwordx4 %2, %16, off offset:128 sc0\n\t"
    "global_load_dwordx4 %3, %16, off offset:192 sc0\n\t"
    "global_load_dwordx4 %4, %16, off offset:256 sc0\n\t"
    "global_load_dwordx4 %5, %16, off offset:320 sc0\n\t"
    "global_load_dwordx4 %6, %16, off offset:384 sc0\n\t"
    "global_load_dwordx4 %7, %16, off offset:448 sc0\n\t"
    "global_load_dwordx4 %8, %16, off offset:512 sc0\n\t"
    "global_load_dwordx4 %9, %16, off offset:576 sc0\n\t"
    "global_load_dwordx4 %10, %16, off offset:640 sc0\n\t"
    "global_load_dwordx4 %11, %16, off offset:704 sc0\n\t"
    "global_load_dwordx4 %12, %16, off offset:768 sc0\n\t"
    "global_load_dwordx4 %13, %16, off offset:832 sc0\n\t"
    "global_load_dwordx4 %14, %16, off offset:896 sc0\n\t"
    "global_load_dwordx4 %15, %16, off offset:960 sc0\n\t"
    "s_waitcnt vmcnt(0)"
    : "=&v"(o[0]),"=&v"(o[1]),"=&v"(o[2]),"=&v"(o[3]),
      "=&v"(o[4]),"=&v"(o[5]),"=&v"(o[6]),"=&v"(o[7]),
      "=&v"(o[8]),"=&v"(o[9]),"=&v"(o[10]),"=&v"(o[11]),
      "=&v"(o[12]),"=&v"(o[13]),"=&v"(o[14]),"=&v"(o[15])
    : "v"(p) : "memory");
}
__device__ inline void ld8_sc0(const void* p, short8* o){
  asm volatile(
    "global_load_dwordx4 %0, %8, off sc0\n\t"
    "global_load_dwordx4 %1, %8, off offset:64 sc0\n\t"
    "global_load_dwordx4 %2, %8, off offset:128 sc0\n\t"
    "global_load_dwordx4 %3, %8, off offset:192 sc0\n\t"
    "global_load_dwordx4 %4, %8, off offset:256 sc0\n\t"
    "global_load_dwordx4 %5, %8, off offset:320 sc0\n\t"
    "global_load_dwordx4 %6, %8, off offset:384 sc0\n\t"
    "global_load_dwordx4 %7, %8, off offset:448 sc0\n\t"
    "s_waitcnt vmcnt(0)"
    : "=&v"(o[0]),"=&v"(o[1]),"=&v"(o[2]),"=&v"(o[3]),
      "=&v"(o[4]),"=&v"(o[5]),"=&v"(o[6]),"=&v"(o[7])
    : "v"(p) : "memory");
}
__device__ inline void ld3_sc0(const float* p0, const float* p1, const float* p2,
                               f32x4& a, f32x4& b, f32x4& c){
  asm volatile(
    "global_load_dwordx4 %0, %3, off sc0\n\t"
    "global_load_dwordx4 %1, %4, off sc0\n\t"
    "global_load_dwordx4 %2, %5, off sc0\n\t"
    "s_waitcnt vmcnt(0)"
    : "=&v"(a), "=&v"(b), "=&v"(c)
    : "v"(p0), "v"(p1), "v"(p2) : "memory");
}
__device__ inline f32x4 ld1_sc0(const float* p){
  f32x4 a;
  asm volatile(
    "global_load_dwordx4 %0, %1, off sc0\n\t"
    "s_waitcnt vmcnt(0)"
    : "=&v"(a) : "v"(p) : "memory");
  return a;
}

// 256-thread block reduction of two values (sum, sumsq)
__device__ inline void block_reduce2(float& a, float& b, float* sm){
  __syncthreads();
  for(int off=32; off>0; off>>=1){
    a += __shfl_down(a, off);
    b += __shfl_down(b, off);
  }
  int w = threadIdx.x >> 6;
  if((threadIdx.x & 63) == 0){ sm[2*w] = a; sm[2*w+1] = b; }
  __syncthreads();
  a = sm[0]+sm[2]+sm[4]+sm[6];
  b = sm[1]+sm[3]+sm[5]+sm[7];
}

// ---- one-time global barrier (agent scope, slot-per-block) ----
__device__ inline void gbar_once(int* arr, int* rel, int bid){
  __syncthreads();
  if(threadIdx.x==0)
    __hip_atomic_store(&arr[bid*16], 1, __ATOMIC_RELAXED, __HIP_MEMORY_SCOPE_AGENT);
  if(bid==0){
    for(int s=threadIdx.x; s<NBLK; s+=256){
      int it=0;
      while(__hip_atomic_load(&arr[s*16], __ATOMIC_RELAXED, __HIP_MEMORY_SCOPE_AGENT) < 1){
        __builtin_amdgcn_s_sleep(2);
        if(++it > (1<<16)) break;
      }
    }
    __syncthreads();
    if(threadIdx.x==0)
      __hip_atomic_store(rel, 1, __ATOMIC_RELAXED, __HIP_MEMORY_SCOPE_AGENT);
  } else {
    if(threadIdx.x==0){
      int it=0;
      while(__hip_atomic_load(rel, __ATOMIC_RELAXED, __HIP_MEMORY_SCOPE_AGENT) < 1){
        __builtin_amdgcn_s_sleep(2);
        if(++it > (1<<16)) break;
      }
    }
    __syncthreads();
  }
}

// ---- intra-XCD barrier: counter RMW in local L2 (workgroup scope),
//      release via coherence point (agent). Timeout valve: fail, not hang. ----
__device__ inline void xbar(int* xcnt, int* xrel, int G, int ep){
  __syncthreads();   // drains vmcnt: all this block's stores are in L2 first
  if(threadIdx.x==0){
    int old = __hip_atomic_fetch_add(xcnt, 1, __ATOMIC_RELAXED, __HIP_MEMORY_SCOPE_WORKGROUP);
    if(old == G-1){
      __hip_atomic_store(xcnt, 0, __ATOMIC_RELAXED, __HIP_MEMORY_SCOPE_WORKGROUP);
      asm volatile("s_waitcnt vmcnt(0)" ::: "memory");   // reset lands before release
      __hip_atomic_store(xrel, ep, __ATOMIC_RELAXED, __HIP_MEMORY_SCOPE_AGENT);
    } else {
      int it=0;
      while(__hip_atomic_load(xrel, __ATOMIC_RELAXED, __HIP_MEMORY_SCOPE_AGENT) < ep){
        __builtin_amdgcn_s_sleep(2);
        if(++it > (1<<14)) break;
      }
    }
  }
  __syncthreads();
}

// ---- detect float dtype; also zero barrier state ----
__global__ void k_detect_dtype(const unsigned short* emb, int* dflag, int* bar){
  __shared__ int cnt;
  for(int i=threadIdx.x; i<BAR_INTS; i+=256) bar[i] = 0;
  if(threadIdx.x==0) cnt = 0;
  __syncthreads();
  int c = 0;
  for(int i=threadIdx.x; i<2048; i+=256){
    unsigned short u = emb[2*i];
    int exp8 = (u >> 7) & 0xFF;
    if(exp8 > 140) c++;
  }
  atomicAdd(&cnt, c);
  __syncthreads();
  if(threadIdx.x==0) dflag[0] = (cnt < 100) ? 1 : 0;
}

// ---- detect is_first encoding ----
__global__ void k_detect_isf(const unsigned char* isf, int* dflag){
  __shared__ int f_bf, f_f32, f_u8;
  if(threadIdx.x==0){ f_bf=0; f_f32=0; f_u8=0; }
  __syncthreads();
  for(int i=threadIdx.x; i<B_*T_; i+=256){
    unsigned char c = isf[i];
    if(c == 0x3F){
      if((i & 3) == 1) atomicOr(&f_bf, 1);
      else if((i & 3) == 3) atomicOr(&f_f32, 1);
    }
    if(c == 1 && (i & 3) != 0) atomicOr(&f_u8, 1);
  }
  __syncthreads();
  if(threadIdx.x==0)
    dflag[1] = f_bf ? 2 : (f_f32 ? 3 : (f_u8 ? 1 : 0));
}

// ---- batched param conversion -> canonical f32 block ----
struct PDesc { const void* src[17]; int cum[18]; };
__global__ __launch_bounds__(256) void k_params(PDesc pd, float* dst, const int* dflag){
  int g = blockIdx.x*256 + threadIdx.x;
  if(g >= PTOT) return;
  int dt = dflag[0];
  int s = 0;
  while(g >= pd.cum[s+1]) s++;
  int off = g - pd.cum[s];
  dst[g] = dt ? bf2f(((const bf16*)pd.src[s])[off]) : ((const float*)pd.src[s])[off];
}

__global__ void k_cvt_bf(const void* src, bf16* dst, int n, const int* dflag){
  int dt = dflag[0];
  int i0 = (blockIdx.x*256 + threadIdx.x)*4;
  #pragma unroll
  for(int k=0;k<4;k++){
    int i = i0+k;
    if(i < n) dst[i] = dt ? ((const bf16*)src)[i] : f2bf(((const float*)src)[i]);
  }
}

__global__ void k_cvt_f(const void* src, float* dst, int n, const int* dflag){
  int dt = dflag[0];
  int i0 = (blockIdx.x*256 + threadIdx.x)*4;
  #pragma unroll
  for(int k=0;k<4;k++){
    int i = i0+k;
    if(i < n) dst[i] = dt ? bf2f(((const bf16*)src)[i]) : ((const float*)src)[i];
  }
}

// ---- tiled transpose: src[K][N] -> dst[N][K] (bf16), head = blockIdx.y ----
__global__ __launch_bounds__(256) void k_transpose(const void* src, bf16* dst, int K, int N, const int* dflag){
  __shared__ unsigned short t[64][72];
  int dt = dflag[0];
  int tilesN = N/64;
  int tk = blockIdx.x / tilesN, tn = blockIdx.x % tilesN;
  size_t hoff = (size_t)blockIdx.y * K * N;
  unsigned short* d = (unsigned short*)dst + hoff;
  int tx = threadIdx.x & 63, ty0 = threadIdx.x >> 6;
  int k0 = tk*64, n0 = tn*64;
  #pragma unroll
  for(int i=0;i<16;i++){
    int ty = ty0*16+i;
    size_t off = hoff + (size_t)(k0+ty)*N + n0+tx;
    unsigned short v;
    if(dt) v = ((const unsigned short*)src)[off];
    else { bf16 b = f2bf(((const float*)src)[off]); v = *(unsigned short*)&b; }
    t[ty][tx] = v;
  }
  __syncthreads();
  #pragma unroll
  for(int i=0;i<16;i++){ int ty = ty0*16+i; d[(size_t)(n0+ty)*K + k0+tx] = t[tx][ty]; }
}

// ---- cross-wave reduce of NF 16x16 frags (K wave-split), store 16 x NF*16 tile ----
template<int NF>
__device__ inline void wave_dump_reduce(f32x4* acc, float* S, float* dst, int ldd){
  int tid = threadIdx.x, w = tid>>6, lane = tid&63;
  __syncthreads();
  #pragma unroll
  for(int f=0; f<NF; f++) *(f32x4*)&S[(w*NF + f)*256 + lane*4] = acc[f];
  __syncthreads();
  #pragma unroll
  for(int i=0;i<NF;i++){
    int e = tid + 256*i;
    int r = e / (NF*16), c = e % (NF*16);
    int f = c>>4, lane2 = ((r>>2)<<4) | (c&15), g = r&3;
    float v = S[(0*NF+f)*256 + lane2*4 + g] + S[(1*NF+f)*256 + lane2*4 + g]
            + S[(2*NF+f)*256 + lane2*4 + g] + S[(3*NF+f)*256 + lane2*4 + g];
    dst[r*ldd + c] = v;
  }
}

// ---- phase A: z2 tile (NT=64, K=2048, wave-split 512). A = a2X (peer, sc0) ----
__device__ void phA_z2(int tile, const bf16* a2X, const bf16* WgT, float* z2X, float* S){
  int tid=threadIdx.x, w=tid>>6, lane=tid&63, q=lane>>4, lo=lane&15;
  short8 af[16];
  ld16_sc0((const void*)(a2X + (size_t)lo*2048 + w*512 + q*8), af);
  f32x4 acc[4];
  #pragma unroll
  for(int f=0;f<4;f++) acc[f] = (f32x4)0.f;
  const bf16* Bb = WgT + ((size_t)(tile*64 + lo))*2048 + w*512 + q*8;
  #pragma unroll
  for(int j=0;j<16;j++){
    #pragma unroll
    for(int f=0;f<4;f++){
      short8 bv = *(const short8*)(const void*)(Bb + (size_t)f*32768 + 32*j);
      acc[f] = __builtin_amdgcn_mfma_f32_16x16x32_bf16(af[j], bv, acc[f], 0,0,0);
    }
  }
  wave_dump_reduce<4>(acc, S, z2X + tile*64, GRUN_);
}

// ---- phase A: z5-emb tile (NT=64, K=1536, wave-split 384). A = embB (read-only) ----
__device__ void phA_z5e(int tile, int t, int bg0, const bf16* embB, const bf16* W5T,
                        float* z5eX, float* S){
  int tid=threadIdx.x, w=tid>>6, lane=tid&63, q=lane>>4, lo=lane&15;
  f32x4 acc[4];
  #pragma unroll
  for(int f=0;f<4;f++) acc[f] = (f32x4)0.f;
  const bf16* Ar = embB + ((size_t)(bg0+lo)*T_ + t)*EMB_ + w*384 + q*8;
  const bf16* Bb = W5T + ((size_t)(tile*64 + lo))*OBSK_ + 1024 + w*384 + q*8;
  #pragma unroll
  for(int j=0;j<12;j++){
    short8 av = *(const short8*)(const void*)(Ar + 32*j);
    #pragma unroll
    for(int f=0;f<4;f++){
      short8 bv = *(const short8*)(const void*)(Bb + (size_t)f*16*OBSK_ + 32*j);
      acc[f] = __builtin_amdgcn_mfma_f32_16x16x32_bf16(av, bv, acc[f], 0,0,0);
    }
  }
  wave_dump_reduce<4>(acc, S, z5eX + tile*64, HID_);
}

// ---- phase C: z3 / z5-deter tile (NT=32, K=1024, wave-split 256). A = deterBX (peer) ----
__device__ void phC(int job, int idx, const bf16* deterBX, const bf16* W3T, const bf16* W5T,
                    float* z3X, float* z5X, float* S){
  int tid=threadIdx.x, w=tid>>6, lane=tid&63, q=lane>>4, lo=lane&15;
  int tile = job & 31;
  bool isz3 = job < 32;
  const bf16* BT; int ldb; float* dst;
  if(isz3){ BT = W3T + (size_t)idx*DETER_*HID_ + (size_t)tile*32*DETER_; ldb = DETER_; dst = z3X; }
  else    { BT = W5T + (size_t)tile*32*OBSK_;                            ldb = OBSK_;  dst = z5X; }
  short8 af[8];
  ld8_sc0((const void*)(deterBX + (size_t)lo*1024 + w*256 + q*8), af);
  f32x4 acc[2];
  acc[0]=(f32x4)0.f; acc[1]=(f32x4)0.f;
  const bf16* Bb = BT + (size_t)lo*ldb + w*256 + q*8;
  #pragma unroll
  for(int j=0;j<8;j++){
    #pragma unroll
    for(int f=0;f<2;f++){
      short8 bv = *(const short8*)(const void*)(Bb + (size_t)(f*16)*ldb + 32*j);
      acc[f] = __builtin_amdgcn_mfma_f32_16x16x32_bf16(af[j], bv, acc[f], 0,0,0);
    }
  }
  wave_dump_reduce<2>(acc, S, dst + tile*32, HID_);
}

// ---- phase B: GRU row (thread map h = tid*4 + jj) ----
__device__ void phB_row(int r, int bg, int t, int dt, const float* z2X, const float* paramF,
                        float* deterX, float* determX, bf16* deterBX, void* out, float* S){
  __syncthreads();
  int tid = threadIdx.x;
  const float* base = z2X + r*GRUN_ + tid*4;
  f32x4 zr, zc, zu;
  ld3_sc0(base, base+1024, base+2048, zr, zc, zu);
  float s=0.f, s2=0.f;
  #pragma unroll
  for(int jj=0;jj<4;jj++){
    int h = tid*4+jj;
    zr[jj] += paramF[Pbg + h];
    zc[jj] += paramF[Pbg + 1024 + h];
    zu[jj] += paramF[Pbg + 2048 + h];
    s += zr[jj]+zc[jj]+zu[jj];
    s2 += zr[jj]*zr[jj] + zc[jj]*zc[jj] + zu[jj]*zu[jj];
  }
  block_reduce2(s, s2, S);
  float mean = s/GRUN_, var = s2/GRUN_ - mean*mean;
  float rstd = rsqrtf(fmaxf(var,0.f) + 1e-5f);
  f32x4 dm = *(const f32x4*)(determX + r*DETER_ + tid*4);   // owner-block only
  #pragma unroll
  for(int jj=0;jj<4;jj++){
    int h = tid*4+jj;
    float lnr = (zr[jj]-mean)*rstd*paramF[Pgg+h]      + paramF[Pbng+h];
    float lnc = (zc[jj]-mean)*rstd*paramF[Pgg+1024+h] + paramF[Pbng+1024+h];
    float lnu = (zu[jj]-mean)*rstd*paramF[Pgg+2048+h] + paramF[Pbng+2048+h];
    float reset = sigm_(lnr);
    float cand  = tanhf(reset*lnc);
    float upd   = sigm_(lnu - 1.f);     // UPDATE_BIAS
    float dn = upd*cand + (1.f-upd)*dm[jj];
    deterX[r*DETER_ + h] = dn;          // owner
    deterBX[r*DETER_ + h] = f2bf(dn);   // publish (plain store -> local L2)
    stout(out, dt, ((size_t)bg*T_+t)*OUTW_ + 192 + h, dn);
  }
}

// ---- phase D: heads + outputs + step_in(t+1) ----
__device__ void phD_row(int r, int bg, int t, int dt, int enc, int idx,
                        const float* z3X, const float* z5X, const float* z5eX,
                        const float* paramF, const float* actF, const void* isf,
                        const float* deterX, float* determX, bf16* a2X,
                        void* out, float* S){
  float* hs   = S;
  float* xo   = S + 1024;
  float* red  = S + 2048;
  float* dsO  = S + 2304;
  float* in44 = S + 2432;
  float* sm   = S + 2496;
  int tid = threadIdx.x;
  __syncthreads();
  f32x4 a3  = ld1_sc0(z3X  + r*HID_ + tid*4);
  f32x4 a5  = ld1_sc0(z5X  + r*HID_ + tid*4);
  f32x4 a5e = ld1_sc0(z5eX + r*HID_ + tid*4);
  f32x4 z3v, z5v;
  float s3=0.f,q3=0.f,s5=0.f,q5=0.f;
  #pragma unroll
  for(int jj=0;jj<4;jj++){
    int h = tid*4+jj;
    z3v[jj] = a3[jj] + paramF[Pb3 + idx*HID_ + h];
    s3 += z3v[jj]; q3 += z3v[jj]*z3v[jj];
    z5v[jj] = a5[jj] + a5e[jj] + paramF[Pb5 + h];
    s5 += z5v[jj]; q5 += z5v[jj]*z5v[jj];
  }
  block_reduce2(s3, q3, sm);
  block_reduce2(s5, q5, sm);
  float m3=s3/HID_, v3=q3/HID_-m3*m3, r3=rsqrtf(fmaxf(v3,0.f)+1e-5f);
  float m5=s5/HID_, v5=q5/HID_-m5*m5, r5=rsqrtf(fmaxf(v5,0.f)+1e-5f);
  #pragma unroll
  for(int jj=0;jj<4;jj++){
    int h = tid*4+jj;
    hs[h] = elu_((z3v[jj]-m3)*r3*paramF[Pg3+idx*HID_+h] + paramF[Pbn3+idx*HID_+h]);
    xo[h] = elu_((z5v[jj]-m5)*r5*paramF[Pg5+h] + paramF[Pbn5+h]);
  }
  __syncthreads();
  int j = tid & 63, cch = tid >> 6;
  {
    const float* W = paramF + PW4 + (size_t)idx*HID_*64;
    float a = 0.f;
    for(int k=cch*256; k<cch*256+256; k++) a += hs[k]*W[k*64 + j];
    red[tid] = a;
    __syncthreads();
    if(tid < 64) dsO[tid] = red[tid]+red[tid+64]+red[tid+128]+red[tid+192] + paramF[Pb4+idx*64+tid];
    __syncthreads();
    const float* W6f = paramF + PW6;
    a = 0.f;
    for(int k=cch*256; k<cch*256+256; k++) a += xo[k]*W6f[k*64 + j];
    red[tid] = a;
    __syncthreads();
    if(tid < 64) dsO[64+tid] = red[tid]+red[tid+64]+red[tid+128]+red[tid+192] + paramF[Pb6+tid];
    __syncthreads();
  }
  size_t ob = ((size_t)bg*T_ + t)*OUTW_;
  if(tid < 32){
    float pm = dsO[tid];
    float ps = softplus_(dsO[32+tid]) + 0.1f;
    float om = dsO[64+tid];
    float os = softplus_(dsO[96+tid]) + 0.1f;
    stout(out, dt, ob+tid,      om);   // omean
    stout(out, dt, ob+32+tid,   os);   // ostd
    stout(out, dt, ob+64+tid,   om);   // post_stoch
    stout(out, dt, ob+96+tid,   pm);   // pmean
    stout(out, dt, ob+128+tid,  ps);   // pstd
    stout(out, dt, ob+160+tid,  pm);   // prior_stoch
  }
  if(t+1 < T_){
    float m = maskv(isf, enc, bg*T_ + (t+1));
    if(tid < 32)       in44[tid] = dsO[64+tid]*m;
    else if(tid < 44)  in44[tid] = actF[(size_t)(bg*T_+(t+1))*ACT_ + (tid-32)]*m;
    __syncthreads();
    const float* W1f = paramF + PW1;
    f32x4 accv = *(const f32x4*)(paramF + Pb1 + tid*4);
    for(int k=0;k<STOCH_+ACT_;k++){
      float ik = in44[k];
      f32x4 wv = *(const f32x4*)(W1f + (size_t)k*HID_ + tid*4);
      accv += wv*ik;
    }
    float s=0.f, s2=0.f;
    #pragma unroll
    for(int jj=0;jj<4;jj++){ s += accv[jj]; s2 += accv[jj]*accv[jj]; }
    block_reduce2(s, s2, sm);
    float mean = s/HID_, var = s2/HID_ - mean*mean;
    float rstd = rsqrtf(fmaxf(var,0.f) + 1e-5f);
    #pragma unroll
    for(int jj=0;jj<4;jj++){
      int h = tid*4+jj;
      float xv = (accv[jj]-mean)*rstd*paramF[Pg1+h] + paramF[Pbn1+h];
      a2X[r*GRUK_ + h] = f2bf(elu_(xv));              // publish
      float dmv = deterX[r*DETER_+h]*m;
      determX[r*DETER_+h] = dmv;                      // owner
      a2X[r*GRUK_ + HID_ + h] = f2bf(dmv);            // publish
    }
  }
}

// ---- init: step_in for t=0 with zero carry state ----
__device__ void init_row(int r, int bg, int enc, const float* actF, const void* isf,
                         const float* paramF, float* determX, bf16* a2X, float* S){
  float* in44 = S;
  float* sm   = S + 64;
  int tid = threadIdx.x;
  __syncthreads();
  float m = maskv(isf, enc, bg*T_);
  if(tid < 32)       in44[tid] = 0.f;
  else if(tid < 44)  in44[tid] = actF[(size_t)(bg*T_)*ACT_ + (tid-32)]*m;
  __syncthreads();
  const float* W1f = paramF + PW1;
  f32x4 accv = *(const f32x4*)(paramF + Pb1 + tid*4);
  for(int k=0;k<STOCH_+ACT_;k++){
    float ik = in44[k];
    f32x4 wv = *(const f32x4*)(W1f + (size_t)k*HID_ + tid*4);
    accv += wv*ik;
  }
  float s=0.f, s2=0.f;
  #pragma unroll
  for(int jj=0;jj<4;jj++){ s += accv[jj]; s2 += accv[jj]*accv[jj]; }
  block_reduce2(s, s2, sm);
  float mean = s/HID_, var = s2/HID_ - mean*mean;
  float rstd = rsqrtf(fmaxf(var,0.f) + 1e-5f);
  #pragma unroll
  for(int jj=0;jj<4;jj++){
    int h = tid*4+jj;
    float xv = (accv[jj]-mean)*rstd*paramF[Pg1+h] + paramF[Pbn1+h];
    a2X[r*GRUK_ + h] = f2bf(elu_(xv));
    determX[r*DETER_+h] = 0.f;
    a2X[r*GRUK_ + HID_ + h] = f2bf(0.f);
  }
}

// ---- persistent batch-partitioned scan: one XCD group owns 16 batch rows ----
__global__ __launch_bounds__(256,2) void k_scan(
    const bf16* WgT, const bf16* W3T, const bf16* W5T, const bf16* embB,
    const float* paramF, const float* actF, const void* isf,
    const int* dflag, const int* ens_ix, void* out,
    char* xscr, int* bar)
{
  __shared__ float S[4096];    // 16 KB
  __shared__ int shc[6];
  int tid = threadIdx.x, bid = blockIdx.x;
  int dt  = dflag[0];
  int enc = dflag[1];
  // ---- register into physical-XCD group ----
  if(tid == 0){
    int x;
    asm volatile("s_getreg_b32 %0, hwreg(20, 0, 4)" : "=s"(x));   // HW_REG_XCC_ID
    x &= 15;
    shc[0] = x;
    shc[1] = __hip_atomic_fetch_add(&bar[C_CNT + x], 1, __ATOMIC_RELAXED, __HIP_MEMORY_SCOPE_AGENT);
  }
  __syncthreads();
  gbar_once(bar + C_ARR, bar + C_REL, bid);   // one-time: all registrations visible
  if(tid == 0){
    int ne = 0, slot = 0;
    for(int x=0; x<16; x++){
      int c = __hip_atomic_load(&bar[C_CNT + x], __ATOMIC_RELAXED, __HIP_MEMORY_SCOPE_AGENT);
      if(c > 0){ ne++; if(x < shc[0]) slot++; }
    }
    shc[2] = __hip_atomic_load(&bar[C_CNT + shc[0]], __ATOMIC_RELAXED, __HIP_MEMORY_SCOPE_AGENT);
    shc[3] = ne; shc[4] = slot;
  }
  __syncthreads();
  int xcd = shc[0], rank = shc[1], G = shc[2], nne = shc[3], slot = shc[4];
  int x8 = xcd & 7;
  char* xb = xscr + (size_t)x8 * XSZ;
  float* z2X     = (float*)(xb + XO_Z2);
  float* z3X     = (float*)(xb + XO_Z3);
  float* z5X     = (float*)(xb + XO_Z5);
  float* z5eX    = (float*)(xb + XO_Z5E);
  float* deterX  = (float*)(xb + XO_DET);
  float* determX = (float*)(xb + XO_DETM);
  bf16*  deterBX = (bf16*) (xb + XO_DETB);
  bf16*  a2X     = (bf16*) (xb + XO_A2);
  int* xcnt = &bar[C_XBAR + x8*32];
  int* xrel = &bar[C_XBAR + x8*32 + 16];
  int ep = 0;
  // batch-groups of 16 rows; normally nne==8 -> one group per XCD
  for(int g = slot; g < 8; g += nne){
    int bg0 = g*16;
    for(int r = rank; r < 16; r += G)
      init_row(r, bg0+r, enc, actF, isf, paramF, determX, a2X, S);
    xbar(xcnt, xrel, G, ++ep);
    for(int t=0; t<T_; t++){
      int idx = ens_ix[t];
      // Phase A: z2 (48 tiles) + z5-emb (16 tiles)
      for(int j = rank; j < 64; j += G){
        if(j < 48) phA_z2(j, a2X, WgT, z2X, S);
        else       phA_z5e(j-48, t, bg0, embB, W5T, z5eX, S);
      }
      xbar(xcnt, xrel, G, ++ep);
      // Phase B: GRU rows
      for(int r = rank; r < 16; r += G)
        phB_row(r, bg0+r, t, dt, z2X, paramF, deterX, determX, deterBX, out, S);
      xbar(xcnt, xrel, G, ++ep);
      // Phase C: z3 (32 tiles) + z5-deter (32 tiles)
      for(int j = rank; j < 64; j += G)
        phC(j, idx, deterBX, W3T, W5T, z3X, z5X, S);
      xbar(xcnt, xrel, G, ++ep);
      // Phase D: heads + outputs + step_in(t+1)
      for(int r = rank; r < 16; r += G)
        phD_row(r, bg0+r, t, dt, enc, idx, z3X, z5X, z5eX, paramF, actF, isf,
                deterX, determX, a2X, out, S);
      xbar(xcnt, xrel, G, ++ep);
    }
  }
}

extern "C" void kernel_launch(void* const* d_in, const int* in_sizes, int n_in,
                              void* d_out, int out_size, void* d_ws, size_t ws_size,
                              hipStream_t stream)
{
  const void* embed  = d_in[0];
  const void* action = d_in[1];
  const void* isf    = d_in[2];
  const int*  ens_ix = (const int*)d_in[3];

  char* ws = (char*)d_ws;
  bf16*  WgT    = (bf16*) (ws + 0);            // 12.58 MB
  bf16*  W3T    = (bf16*) (ws + 12582912);     // 10.49 MB
  bf16*  W5T    = (bf16*) (ws + 23068672);     // 5.24 MB
  float* paramF = (float*)(ws + 28311552);     // 1.88 MB
  bf16*  embB   = (bf16*) (ws + 30189056);     // 25.17 MB
  float* actF   = (float*)(ws + 55354880);     // 0.39 MB
  char*  xscr   =         (ws + 55748096);     // 8 x 640 KB = 5.24 MB
  int*   dflag  = (int*)  (ws + 60990976);
  int*   bar    = (int*)  (ws + 60992000);     // 64 KB barrier state

  k_detect_dtype<<<1,256,0,stream>>>((const unsigned short*)embed, dflag, bar);
  k_detect_isf<<<1,256,0,stream>>>((const unsigned char*)isf, dflag);

  PDesc pd;
  const int srcidx[17] = {4,5,6,7, 9,10,11, 13,14,15, 17, 19,20,21, 23, 16, 22};
  const int sizes[17]  = {45056,1024,1024,1024, 3072,3072,3072, 5120,5120,5120,
                          320, 1024,1024,1024, 64, 327680, 65536};
  int cum = 0;
  for(int i=0;i<17;i++){ pd.src[i] = d_in[srcidx[i]]; pd.cum[i] = cum; cum += sizes[i]; }
  pd.cum[17] = cum;  // 469376
  k_params<<<(PTOT+255)/256, 256, 0, stream>>>(pd, paramF, dflag);

  k_cvt_bf<<<(B_*T_*EMB_)/1024, 256, 0, stream>>>(embed, embB, B_*T_*EMB_, dflag);
  k_cvt_f<<<(B_*T_*ACT_+1023)/1024, 256, 0, stream>>>(action, actF, B_*T_*ACT_, dflag);

  k_transpose<<<dim3((GRUK_/64)*(GRUN_/64),1), 256, 0, stream>>>(d_in[8],  WgT, GRUK_, GRUN_, dflag);
  k_transpose<<<dim3((DETER_/64)*(HID_/64),5), 256, 0, stream>>>(d_in[12], W3T, DETER_, HID_, dflag);
  k_transpose<<<dim3((OBSK_/64)*(HID_/64),1), 256, 0, stream>>>(d_in[18], W5T, OBSK_, HID_, dflag);

  // one persistent kernel: batch partitioned across physical XCDs,
  // all synchronization and state exchange XCD-local (L2-coherent)
  k_scan<<<NBLK,256,0,stream>>>(WgT, W3T, W5T, embB, paramF, actF, isf,
                                dflag, ens_ix, d_out, xscr, bar);
}

// Round 4
// 3876.112 us; speedup vs baseline: 4.5810x; 3.2910x over previous
//
#include <hip/hip_runtime.h>
#include <hip/hip_bf16.h>
#include <math.h>

using bf16 = __hip_bfloat16;
using short8 = __attribute__((ext_vector_type(8))) short;
using f32x4  = __attribute__((ext_vector_type(4))) float;

#define B_     128
#define T_     64
#define EMB_   1536
#define ACT_   12
#define STOCH_ 32
#define DETER_ 1024
#define HID_   1024
#define GRUN_  3072
#define GRUK_  2048
#define OBSK_  2560
#define OUTW_  1216   // 6*STOCH + DETER

// canonical f32 param block offsets (floats)
#define PW1   0
#define Pb1   45056
#define Pg1   46080
#define Pbn1  47104
#define Pbg   48128
#define Pgg   51200
#define Pbng  54272
#define Pb3   57344
#define Pg3   62464
#define Pbn3  67584
#define Pb4   72704
#define Pb5   73024
#define Pg5   74048
#define Pbn5  75072
#define Pb6   76096
#define PW4   76160
#define PW6   403840
#define PTOT  469376

__device__ inline float bf2f(bf16 v){ return __bfloat162float(v); }
__device__ inline bf16  f2bf(float v){ return __float2bfloat16(v); }
__device__ inline float elu_(float x){ return x > 0.f ? x : expm1f(x); }
__device__ inline float sigm_(float x){ return 1.f/(1.f+expf(-x)); }
__device__ inline float softplus_(float x){ return fmaxf(x,0.f) + log1pf(expf(-fabsf(x))); }
__device__ inline void stout(void* out, int dt, size_t i, float v){
  if(dt) ((bf16*)out)[i] = f2bf(v); else ((float*)out)[i] = v;
}
__device__ inline float maskv(const void* isf, int enc, int idx){
  float fv;
  if(enc==0)      fv = (float)((const int*)isf)[idx];
  else if(enc==1) fv = (float)((const unsigned char*)isf)[idx];
  else if(enc==2) fv = bf2f(((const bf16*)isf)[idx]);
  else            fv = ((const float*)isf)[idx];
  return (fv != 0.f) ? 0.f : 1.f;
}

// 256-thread block reduction of two values (sum, sumsq)
__device__ inline void block_reduce2(float& a, float& b, float* sm){
  __syncthreads();
  for(int off=32; off>0; off>>=1){
    a += __shfl_down(a, off);
    b += __shfl_down(b, off);
  }
  int w = threadIdx.x >> 6;
  if((threadIdx.x & 63) == 0){ sm[2*w] = a; sm[2*w+1] = b; }
  __syncthreads();
  a = sm[0]+sm[2]+sm[4]+sm[6];
  b = sm[1]+sm[3]+sm[5]+sm[7];
}

// ---- detect float dtype from embed buffer: dflag[0] = 1 if bf16, 0 if f32 ----
__global__ void k_detect_dtype(const unsigned short* emb, int* dflag){
  __shared__ int cnt;
  if(threadIdx.x==0) cnt = 0;
  __syncthreads();
  int c = 0;
  for(int i=threadIdx.x; i<2048; i+=256){
    unsigned short u = emb[2*i];
    int exp8 = (u >> 7) & 0xFF;
    if(exp8 > 140) c++;
  }
  atomicAdd(&cnt, c);
  __syncthreads();
  if(threadIdx.x==0) dflag[0] = (cnt < 100) ? 1 : 0;
}

// ---- detect is_first encoding: dflag[1] = 0 int32, 1 uint8, 2 bf16, 3 f32 ----
__global__ void k_detect_isf(const unsigned char* isf, int* dflag){
  __shared__ int f_bf, f_f32, f_u8;
  if(threadIdx.x==0){ f_bf=0; f_f32=0; f_u8=0; }
  __syncthreads();
  for(int i=threadIdx.x; i<B_*T_; i+=256){
    unsigned char c = isf[i];
    if(c == 0x3F){
      if((i & 3) == 1) atomicOr(&f_bf, 1);
      else if((i & 3) == 3) atomicOr(&f_f32, 1);
    }
    if(c == 1 && (i & 3) != 0) atomicOr(&f_u8, 1);
  }
  __syncthreads();
  if(threadIdx.x==0)
    dflag[1] = f_bf ? 2 : (f_f32 ? 3 : (f_u8 ? 1 : 0));
}

// ---- batched param conversion -> canonical f32 block ----
struct PDesc { const void* src[17]; int cum[18]; };
__global__ __launch_bounds__(256) void k_params(PDesc pd, float* dst, const int* dflag){
  int g = blockIdx.x*256 + threadIdx.x;
  if(g >= PTOT) return;
  int dt = dflag[0];
  int s = 0;
  while(g >= pd.cum[s+1]) s++;
  int off = g - pd.cum[s];
  dst[g] = dt ? bf2f(((const bf16*)pd.src[s])[off]) : ((const float*)pd.src[s])[off];
}

__global__ void k_cvt_bf(const void* src, bf16* dst, int n, const int* dflag){
  int dt = dflag[0];
  int i0 = (blockIdx.x*256 + threadIdx.x)*4;
  #pragma unroll
  for(int k=0;k<4;k++){
    int i = i0+k;
    if(i < n) dst[i] = dt ? ((const bf16*)src)[i] : f2bf(((const float*)src)[i]);
  }
}

__global__ void k_cvt_f(const void* src, float* dst, int n, const int* dflag){
  int dt = dflag[0];
  int i0 = (blockIdx.x*256 + threadIdx.x)*4;
  #pragma unroll
  for(int k=0;k<4;k++){
    int i = i0+k;
    if(i < n) dst[i] = dt ? bf2f(((const bf16*)src)[i]) : ((const float*)src)[i];
  }
}

// ---- tiled transpose: src[K][N] -> dst[N][K] (bf16 canonical), head = blockIdx.y ----
__global__ __launch_bounds__(256) void k_transpose(const void* src, bf16* dst, int K, int N, const int* dflag){
  __shared__ unsigned short t[64][72];
  int dt = dflag[0];
  int tilesN = N/64;
  int tk = blockIdx.x / tilesN, tn = blockIdx.x % tilesN;
  size_t hoff = (size_t)blockIdx.y * K * N;
  unsigned short* d = (unsigned short*)dst + hoff;
  int tx = threadIdx.x & 63, ty0 = threadIdx.x >> 6;
  int k0 = tk*64, n0 = tn*64;
  #pragma unroll
  for(int i=0;i<16;i++){
    int ty = ty0*16+i;
    size_t off = hoff + (size_t)(k0+ty)*N + n0+tx;
    unsigned short v;
    if(dt) v = ((const unsigned short*)src)[off];
    else { bf16 b = f2bf(((const float*)src)[off]); v = *(unsigned short*)&b; }
    t[ty][tx] = v;
  }
  __syncthreads();
  #pragma unroll
  for(int i=0;i<16;i++){ int ty = ty0*16+i; d[(size_t)(n0+ty)*K + k0+tx] = t[tx][ty]; }
}

// ---- MFMA GEMM: 128x32 output tile per block, K split over 4 waves, LDS reduce ----
// mode 0 (grid 256):
//   bid<192: z2p[part] = A2[128,2048] @ WgT tile (N=3072; ct=bid%96, part=bid/96, Kc=1024)
//   bid>=192: z5p[2+part] = embB[:,t,:] @ W5T[:,1024:] tile (32 ct x 2 parts, Kc=768)
//             -- independent of the recurrence state; uses the 64 CUs idle in z2
// mode 1 (grid 96):
//   bid<32:  z3 = deterB @ W3T[idx] tile (K=1024)
//   bid>=32: z5p[part] = deterB @ W5T[:, :1024] tile (32 ct x 2 parts, Kc=512)
__global__ __launch_bounds__(256) void k_gemm(
    int mode, int t,
    const bf16* A2, const bf16* deterB, const bf16* embB,
    const bf16* WgT, const bf16* W3T, const bf16* W5T,
    float* z2p, float* z3buf, float* z5p, const int* ens_index)
{
  __shared__ float red[8192];   // 32 KB: 2 slots x (16 frag-blocks x 256 floats)
  int bid = blockIdx.x;
  const bf16 *A0 = nullptr, *A1 = nullptr, *BT; float* Cdst;
  int N, ldb, s0 = 0, s1 = 0, split = 1<<30, k0, kc;
  if(mode == 0){
    if(bid < 192){
      int ct = bid % 96, part = bid / 96;
      N = GRUN_; ldb = GRUK_; BT = WgT + (size_t)ct*32*GRUK_;
      A0 = A2; s0 = GRUK_;
      k0 = part*1024; kc = 1024;
      Cdst = z2p + (size_t)part*B_*GRUN_ + ct*32;
    } else {
      int b2 = bid - 192;
      int ct = b2 & 31, part = b2 >> 5;
      N = HID_; ldb = OBSK_; BT = W5T + (size_t)ct*32*OBSK_;
      split = DETER_;
      A1 = embB + (size_t)t*EMB_; s1 = T_*EMB_;
      k0 = 1024 + part*768; kc = 768;
      Cdst = z5p + (size_t)(2+part)*B_*HID_ + ct*32;
    }
  } else if(bid < 32){
    int ct = bid;
    int idx = ens_index[t];
    N = HID_; ldb = DETER_; BT = W3T + (size_t)idx*DETER_*HID_ + (size_t)ct*32*DETER_;
    A0 = deterB; s0 = DETER_;
    k0 = 0; kc = 1024;
    Cdst = z3buf + ct*32;
  } else {
    int b2 = bid - 32;
    int ct = b2 & 31, part = b2 >> 5;
    N = HID_; ldb = OBSK_; BT = W5T + (size_t)ct*32*OBSK_;
    A0 = deterB; s0 = DETER_;
    k0 = part*512; kc = 512;
    Cdst = z5p + (size_t)part*B_*HID_ + ct*32;
  }
  int tid = threadIdx.x;
  int wave = tid >> 6, lane = tid & 63;
  int quad = lane >> 4, lo = lane & 15;
  int kw0 = k0 + wave*(kc>>2), kw1 = kw0 + (kc>>2);
  f32x4 acc[8][2];
  #pragma unroll
  for(int rf=0;rf<8;rf++){ acc[rf][0]=(f32x4)0.f; acc[rf][1]=(f32x4)0.f; }
  for(int kk=kw0; kk<kw1; kk+=32){
    int kf = kk + quad*8;
    const bf16* Ab; int str, ko;
    if(kf < split){ Ab=A0; str=s0; ko=kf; } else { Ab=A1; str=s1; ko=kf-split; }
    short8 af[8], bfg[2];
    #pragma unroll
    for(int rf=0;rf<8;rf++)
      af[rf] = *(const short8*)(const void*)(Ab + (size_t)(16*rf+lo)*str + ko);
    #pragma unroll
    for(int c=0;c<2;c++)
      bfg[c] = *(const short8*)(const void*)(BT + (size_t)(16*c+lo)*ldb + kf);
    #pragma unroll
    for(int rf=0;rf<8;rf++){
      acc[rf][0] = __builtin_amdgcn_mfma_f32_16x16x32_bf16(af[rf], bfg[0], acc[rf][0], 0,0,0);
      acc[rf][1] = __builtin_amdgcn_mfma_f32_16x16x32_bf16(af[rf], bfg[1], acc[rf][1], 0,0,0);
    }
  }
  // cross-wave reduce: waves 2,3 dump -> waves 0,1 add -> waves 0,1 dump -> all sum pairs
  if(wave >= 2){
    #pragma unroll
    for(int rf=0;rf<8;rf++)
      #pragma unroll
      for(int c=0;c<2;c++)
        *(f32x4*)&red[(((wave-2)*16) + rf*2 + c)*256 + lane*4] = acc[rf][c];
  }
  __syncthreads();
  if(wave < 2){
    #pragma unroll
    for(int rf=0;rf<8;rf++)
      #pragma unroll
      for(int c=0;c<2;c++)
        acc[rf][c] += *(const f32x4*)&red[((wave*16) + rf*2 + c)*256 + lane*4];
  }
  __syncthreads();
  if(wave < 2){
    #pragma unroll
    for(int rf=0;rf<8;rf++)
      #pragma unroll
      for(int c=0;c<2;c++)
        *(f32x4*)&red[((wave*16) + rf*2 + c)*256 + lane*4] = acc[rf][c];
  }
  __syncthreads();
  #pragma unroll
  for(int i=0;i<4;i++){
    int r = (tid>>3) + 32*i;
    int col0 = (tid&7)*4;
    int rf = r>>4, rr = r&15, q = rr>>2, g = rr&3;
    f32x4 v;
    #pragma unroll
    for(int j=0;j<4;j++){
      int col = col0+j; int c = col>>4, lo2 = col&15;
      int lane2 = q*16+lo2;
      v[j] = red[(rf*2 + c)*256 + lane2*4 + g]
           + red[(16 + rf*2 + c)*256 + lane2*4 + g];
    }
    *(f32x4*)(Cdst + (size_t)r*N + col0) = v;
  }
}

// ---- reduce z2 parts + bias, LN over 3072, GRU -> deter ----
__global__ __launch_bounds__(256) void k_gru(
    const float* z2p, const float* paramF, const int* dflag,
    const float* determ, float* deter, bf16* deterB, void* out, int t)
{
  __shared__ float sm[8];
  int b = blockIdx.x, tid = threadIdx.x;
  int dt = dflag[0];
  float zz[12]; float s=0.f, s2=0.f;
  #pragma unroll
  for(int i=0;i<12;i++){
    int h = tid + 256*i;
    float acc = paramF[Pbg + h]
              + z2p[(size_t)b*GRUN_ + h]
              + z2p[(size_t)(B_ + b)*GRUN_ + h];
    zz[i]=acc; s+=acc; s2+=acc*acc;
  }
  block_reduce2(s, s2, sm);
  float mean = s/GRUN_, var = s2/GRUN_ - mean*mean;
  float rstd = rsqrtf(fmaxf(var,0.f) + 1e-5f);
  #pragma unroll
  for(int j=0;j<4;j++){
    int h0 = tid + 256*j;
    float lnr = (zz[j]   - mean)*rstd*paramF[Pgg+h0     ] + paramF[Pbng+h0     ];
    float lnc = (zz[j+4] - mean)*rstd*paramF[Pgg+h0+1024] + paramF[Pbng+h0+1024];
    float lnu = (zz[j+8] - mean)*rstd*paramF[Pgg+h0+2048] + paramF[Pbng+h0+2048];
    float reset = sigm_(lnr);
    float cand  = tanhf(reset*lnc);
    float upd   = sigm_(lnu - 1.f);          // UPDATE_BIAS
    float dn = upd*cand + (1.f-upd)*determ[b*DETER_+h0];
    deter[b*DETER_+h0]  = dn;
    deterB[b*DETER_+h0] = f2bf(dn);
    stout(out, dt, ((size_t)b*T_+t)*OUTW_ + 192 + h0, dn);
  }
}

// ---- tail: heads (LN+elu, dist matmuls, outputs) fused with step_in for t+1 ----
__global__ __launch_bounds__(256) void k_tail(
    const float* z3buf, const float* z5p, const float* paramF, const int* dflag,
    const float* actF, const void* isf,
    const float* deter, float* determ, bf16* A2,
    void* out, const int* ens_index, int t)
{
  __shared__ float hs[1024], xo[1024];
  __shared__ float sm[8];
  __shared__ float red[256];
  __shared__ float dsO[128];
  __shared__ float in44[48];
  int b = blockIdx.x, tid = threadIdx.x;
  int dt = dflag[0];
  int idx = ens_index[t];
  float z3v[4], z5v[4]; float s3=0.f,q3=0.f,s5=0.f,q5=0.f;
  #pragma unroll
  for(int i=0;i<4;i++){
    int h = tid + 256*i;
    float a3 = z3buf[(size_t)b*HID_ + h] + paramF[Pb3 + idx*HID_ + h];
    z3v[i]=a3; s3+=a3; q3+=a3*a3;
    float a5 = z5p[(size_t)b*HID_ + h] + z5p[(size_t)(B_ + b)*HID_ + h]
             + z5p[(size_t)(2*B_ + b)*HID_ + h] + z5p[(size_t)(3*B_ + b)*HID_ + h]
             + paramF[Pb5 + h];
    z5v[i]=a5; s5+=a5; q5+=a5*a5;
  }
  block_reduce2(s3, q3, sm);
  block_reduce2(s5, q5, sm);
  float m3=s3/HID_, v3=q3/HID_-m3*m3, r3=rsqrtf(fmaxf(v3,0.f)+1e-5f);
  float m5=s5/HID_, v5=q5/HID_-m5*m5, r5=rsqrtf(fmaxf(v5,0.f)+1e-5f);
  #pragma unroll
  for(int i=0;i<4;i++){
    int h = tid + 256*i;
    hs[h] = elu_((z3v[i]-m3)*r3*paramF[Pg3+idx*HID_+h] + paramF[Pbn3+idx*HID_+h]);
    xo[h] = elu_((z5v[i]-m5)*r5*paramF[Pg5+h] + paramF[Pbn5+h]);
  }
  __syncthreads();
  int j = tid & 63, cch = tid >> 6;
  {
    const float* W = paramF + PW4 + (size_t)idx*HID_*64;
    float a = 0.f;
    for(int k=cch*256; k<cch*256+256; k++) a += hs[k]*W[k*64 + j];
    red[tid] = a;
    __syncthreads();
    if(tid < 64) dsO[tid] = red[tid]+red[tid+64]+red[tid+128]+red[tid+192] + paramF[Pb4+idx*64+tid];
    __syncthreads();
    const float* W6f = paramF + PW6;
    a = 0.f;
    for(int k=cch*256; k<cch*256+256; k++) a += xo[k]*W6f[k*64 + j];
    red[tid] = a;
    __syncthreads();
    if(tid < 64) dsO[64+tid] = red[tid]+red[tid+64]+red[tid+128]+red[tid+192] + paramF[Pb6+tid];
    __syncthreads();
  }
  size_t ob = ((size_t)b*T_ + t)*OUTW_;
  if(tid < 32){
    float pm = dsO[tid];
    float ps = softplus_(dsO[32+tid]) + 0.1f;
    float om = dsO[64+tid];
    float os = softplus_(dsO[96+tid]) + 0.1f;
    stout(out, dt, ob+tid,      om);   // omean
    stout(out, dt, ob+32+tid,   os);   // ostd
    stout(out, dt, ob+64+tid,   om);   // post_stoch
    stout(out, dt, ob+96+tid,   pm);   // pmean
    stout(out, dt, ob+128+tid,  ps);   // pstd
    stout(out, dt, ob+160+tid,  pm);   // prior_stoch
  }
  // ---- step_in for t+1 (block-local stoch carry = dsO[64..95]) ----
  if(t+1 < T_){
    float m = maskv(isf, dflag[1], b*T_ + (t+1));
    if(tid < 32)       in44[tid] = dsO[64+tid]*m;
    else if(tid < 44)  in44[tid] = actF[(size_t)(b*T_+(t+1))*ACT_ + (tid-32)]*m;
    __syncthreads();
    const float* W1f = paramF + PW1;
    float z[4]; float s=0.f, s2=0.f;
    #pragma unroll
    for(int i=0;i<4;i++){
      int h = tid + 256*i;
      float acc = paramF[Pb1 + h];
      for(int k=0;k<STOCH_+ACT_;k++) acc += in44[k]*W1f[k*HID_ + h];
      z[i]=acc; s+=acc; s2+=acc*acc;
    }
    block_reduce2(s, s2, sm);
    float mean = s/HID_, var = s2/HID_ - mean*mean;
    float rstd = rsqrtf(fmaxf(var,0.f) + 1e-5f);
    #pragma unroll
    for(int i=0;i<4;i++){
      int h = tid + 256*i;
      float xv = (z[i]-mean)*rstd*paramF[Pg1+h] + paramF[Pbn1+h];
      A2[(size_t)b*GRUK_ + h] = f2bf(elu_(xv));
      float dm = deter[b*DETER_+h]*m;
      determ[b*DETER_+h] = dm;
      A2[(size_t)b*GRUK_ + HID_ + h] = f2bf(dm);
    }
  }
}

// ---- init: step_in for t=0 with zero carry state ----
__global__ __launch_bounds__(256) void k_init(
    const float* actF, const void* isf, const int* dflag,
    const float* paramF, float* determ, bf16* A2)
{
  __shared__ float in44[48];
  __shared__ float sm[8];
  int b = blockIdx.x, tid = threadIdx.x;
  float m = maskv(isf, dflag[1], b*T_);
  if(tid < 32)       in44[tid] = 0.f;
  else if(tid < 44)  in44[tid] = actF[(size_t)(b*T_)*ACT_ + (tid-32)]*m;
  __syncthreads();
  const float* W1f = paramF + PW1;
  float z[4]; float s=0.f, s2=0.f;
  #pragma unroll
  for(int i=0;i<4;i++){
    int h = tid + 256*i;
    float acc = paramF[Pb1 + h];
    for(int k=0;k<STOCH_+ACT_;k++) acc += in44[k]*W1f[k*HID_ + h];
    z[i]=acc; s+=acc; s2+=acc*acc;
  }
  block_reduce2(s, s2, sm);
  float mean = s/HID_, var = s2/HID_ - mean*mean;
  float rstd = rsqrtf(fmaxf(var,0.f) + 1e-5f);
  #pragma unroll
  for(int i=0;i<4;i++){
    int h = tid + 256*i;
    float xv = (z[i]-mean)*rstd*paramF[Pg1+h] + paramF[Pbn1+h];
    A2[(size_t)b*GRUK_ + h] = f2bf(elu_(xv));
    determ[b*DETER_+h] = 0.f;
    A2[(size_t)b*GRUK_ + HID_ + h] = f2bf(0.f);
  }
}

extern "C" void kernel_launch(void* const* d_in, const int* in_sizes, int n_in,
                              void* d_out, int out_size, void* d_ws, size_t ws_size,
                              hipStream_t stream)
{
  const void* embed  = d_in[0];
  const void* action = d_in[1];
  const void* isf    = d_in[2];
  const int*  ens_ix = (const int*)d_in[3];

  char* ws = (char*)d_ws;
  float* deter  = (float*)(ws + 0);            // 512 KB
  float* determ = (float*)(ws + 524288);       // 512 KB
  bf16*  A2     = (bf16*) (ws + 1048576);      // 512 KB
  bf16*  deterB = (bf16*) (ws + 1572864);      // 256 KB
  float* z2p    = (float*)(ws + 1835008);      // 3 MB  (2 parts x 128x3072 f32)
  float* z3buf  = (float*)(ws + 4980736);      // 512 KB
  float* z5p    = (float*)(ws + 5505024);      // 2 MB  (4 parts: 2 deter + 2 emb)
  bf16*  WgT    = (bf16*) (ws + 7602176);      // 12.6 MB
  bf16*  W3T    = (bf16*) (ws + 20185088);     // 10.5 MB
  bf16*  W5T    = (bf16*) (ws + 30670848);     // 5.2 MB
  float* paramF = (float*)(ws + 35913728);     // 1.88 MB
  bf16*  embB   = (bf16*) (ws + 37791232);     // 25.2 MB
  float* actF   = (float*)(ws + 62957056);     // 0.39 MB
  int*   dflag  = (int*)  (ws + 63350272);

  k_detect_dtype<<<1,256,0,stream>>>((const unsigned short*)embed, dflag);
  k_detect_isf<<<1,256,0,stream>>>((const unsigned char*)isf, dflag);

  PDesc pd;
  const int srcidx[17] = {4,5,6,7, 9,10,11, 13,14,15, 17, 19,20,21, 23, 16, 22};
  const int sizes[17]  = {45056,1024,1024,1024, 3072,3072,3072, 5120,5120,5120,
                          320, 1024,1024,1024, 64, 327680, 65536};
  int cum = 0;
  for(int i=0;i<17;i++){ pd.src[i] = d_in[srcidx[i]]; pd.cum[i] = cum; cum += sizes[i]; }
  pd.cum[17] = cum;  // 469376
  k_params<<<(PTOT+255)/256, 256, 0, stream>>>(pd, paramF, dflag);

  k_cvt_bf<<<(B_*T_*EMB_)/1024, 256, 0, stream>>>(embed, embB, B_*T_*EMB_, dflag);
  k_cvt_f<<<(B_*T_*ACT_+1023)/1024, 256, 0, stream>>>(action, actF, B_*T_*ACT_, dflag);

  k_transpose<<<dim3((GRUK_/64)*(GRUN_/64),1), 256, 0, stream>>>(d_in[8],  WgT, GRUK_, GRUN_, dflag);
  k_transpose<<<dim3((DETER_/64)*(HID_/64),5), 256, 0, stream>>>(d_in[12], W3T, DETER_, HID_, dflag);
  k_transpose<<<dim3((OBSK_/64)*(HID_/64),1), 256, 0, stream>>>(d_in[18], W5T, OBSK_, HID_, dflag);

  k_init<<<B_,256,0,stream>>>(actF, isf, dflag, paramF, determ, A2);

  for(int t=0; t<T_; t++){
    k_gemm<<<256,256,0,stream>>>(0, t, A2, deterB, embB, WgT, W3T, W5T, z2p, z3buf, z5p, ens_ix);
    k_gru<<<B_,256,0,stream>>>(z2p, paramF, dflag, determ, deter, deterB, d_out, t);
    k_gemm<<<96,256,0,stream>>>(1, t, A2, deterB, embB, WgT, W3T, W5T, z2p, z3buf, z5p, ens_ix);
    k_tail<<<B_,256,0,stream>>>(z3buf, z5p, paramF, dflag, actF, isf, deter, determ, A2, d_out, ens_ix, t);
  }
}

// Round 5
// 2883.803 us; speedup vs baseline: 6.1573x; 1.3441x over previous
//
#include <hip/hip_runtime.h>
#include <hip/hip_bf16.h>
#include <math.h>

using bf16 = __hip_bfloat16;
using short8 = __attribute__((ext_vector_type(8))) short;
using f32x4  = __attribute__((ext_vector_type(4))) float;

#define B_     128
#define T_     64
#define EMB_   1536
#define ACT_   12
#define STOCH_ 32
#define DETER_ 1024
#define HID_   1024
#define GRUN_  3072
#define GRUK_  2048
#define OBSK_  2560
#define OUTW_  1216   // 6*STOCH + DETER

// canonical f32 param block offsets (floats)
#define PW1   0
#define Pb1   45056
#define Pg1   46080
#define Pbn1  47104
#define Pbg   48128
#define Pgg   51200
#define Pbng  54272
#define Pb3   57344
#define Pg3   62464
#define Pbn3  67584
#define Pb4   72704
#define Pb5   73024
#define Pg5   74048
#define Pbn5  75072
#define Pb6   76096
#define PW4   76160
#define PW6   403840
#define PTOT  469376

__device__ inline float bf2f(bf16 v){ return __bfloat162float(v); }
__device__ inline bf16  f2bf(float v){ return __float2bfloat16(v); }
__device__ inline float elu_(float x){ return x > 0.f ? x : expm1f(x); }
__device__ inline float sigm_(float x){ return 1.f/(1.f+expf(-x)); }
__device__ inline float softplus_(float x){ return fmaxf(x,0.f) + log1pf(expf(-fabsf(x))); }
__device__ inline void stout(void* out, int dt, size_t i, float v){
  if(dt) ((bf16*)out)[i] = f2bf(v); else ((float*)out)[i] = v;
}
__device__ inline float maskv(const void* isf, int enc, int idx){
  float fv;
  if(enc==0)      fv = (float)((const int*)isf)[idx];
  else if(enc==1) fv = (float)((const unsigned char*)isf)[idx];
  else if(enc==2) fv = bf2f(((const bf16*)isf)[idx]);
  else            fv = ((const float*)isf)[idx];
  return (fv != 0.f) ? 0.f : 1.f;
}

// nw-wave block reduction of two values (sum, sumsq); sm needs 2*nw floats
__device__ inline void block_reduce2w(float& a, float& b, float* sm, int nw){
  __syncthreads();
  for(int off=32; off>0; off>>=1){
    a += __shfl_down(a, off);
    b += __shfl_down(b, off);
  }
  int w = threadIdx.x >> 6;
  if((threadIdx.x & 63) == 0){ sm[2*w] = a; sm[2*w+1] = b; }
  __syncthreads();
  float sa = 0.f, sb = 0.f;
  for(int i=0;i<nw;i++){ sa += sm[2*i]; sb += sm[2*i+1]; }
  a = sa; b = sb;
}

// ---- detect: block 0 = float dtype (dflag[0]); block 1 = is_first enc (dflag[1]) ----
__global__ void k_detect(const unsigned short* emb, const unsigned char* isf, int* dflag){
  __shared__ int c0, c1, c2;
  if(threadIdx.x==0){ c0=0; c1=0; c2=0; }
  __syncthreads();
  if(blockIdx.x == 0){
    int c = 0;
    for(int i=threadIdx.x; i<2048; i+=256){
      unsigned short u = emb[2*i];
      int exp8 = (u >> 7) & 0xFF;
      if(exp8 > 140) c++;
    }
    atomicAdd(&c0, c);
    __syncthreads();
    if(threadIdx.x==0) dflag[0] = (c0 < 100) ? 1 : 0;
  } else {
    for(int i=threadIdx.x; i<B_*T_; i+=256){
      unsigned char c = isf[i];
      if(c == 0x3F){
        if((i & 3) == 1) atomicOr(&c0, 1);
        else if((i & 3) == 3) atomicOr(&c1, 1);
      }
      if(c == 1 && (i & 3) != 0) atomicOr(&c2, 1);
    }
    __syncthreads();
    if(threadIdx.x==0)
      dflag[1] = c0 ? 2 : (c1 ? 3 : (c2 ? 1 : 0));
  }
}

// ---- fused setup: params + cvt_bf + cvt_f + 3 weight transposes, range-partitioned ----
struct PDesc { const void* src[17]; int cum[18]; };
#define SEG0 1834    // params
#define SEG1 12288   // cvt embed -> embB (bf16)
#define SEG2 96      // cvt action -> actF (f32)
#define SEG3 1536    // transpose Wg  (2048x3072)
#define SEG4 1280    // transpose W3  (5 x 1024x1024)
#define SEG5 640     // transpose W5  (2560x1024)

__device__ void transpose_dev(const void* src, bf16* dst, int K, int N,
                              int tk, int tn, int head, int dt,
                              unsigned short (*t)[72]){
  size_t hoff = (size_t)head * K * N;
  unsigned short* d = (unsigned short*)dst + hoff;
  int tx = threadIdx.x & 63, ty0 = threadIdx.x >> 6;
  int k0 = tk*64, n0 = tn*64;
  #pragma unroll
  for(int i=0;i<16;i++){
    int ty = ty0*16+i;
    size_t off = hoff + (size_t)(k0+ty)*N + n0+tx;
    unsigned short v;
    if(dt) v = ((const unsigned short*)src)[off];
    else { bf16 b = f2bf(((const float*)src)[off]); v = *(unsigned short*)&b; }
    t[ty][tx] = v;
  }
  __syncthreads();
  #pragma unroll
  for(int i=0;i<16;i++){ int ty = ty0*16+i; d[(size_t)(n0+ty)*K + k0+tx] = t[tx][ty]; }
}

__global__ __launch_bounds__(256) void k_setup(
    PDesc pd, float* paramF, const int* dflag,
    const void* embed, bf16* embB, const void* action, float* actF,
    const void* w8, bf16* WgT, const void* w12, bf16* W3T,
    const void* w18, bf16* W5T)
{
  __shared__ unsigned short ts[64][72];
  int bid = blockIdx.x, tid = threadIdx.x;
  int dt = dflag[0];
  if(bid < SEG0){
    int g = bid*256 + tid;
    if(g >= PTOT) return;
    int s = 0;
    while(g >= pd.cum[s+1]) s++;
    int off = g - pd.cum[s];
    paramF[g] = dt ? bf2f(((const bf16*)pd.src[s])[off]) : ((const float*)pd.src[s])[off];
    return;
  }
  bid -= SEG0;
  if(bid < SEG1){
    int i0 = (bid*256 + tid)*4;
    #pragma unroll
    for(int k=0;k<4;k++){
      int i = i0+k;
      embB[i] = dt ? ((const bf16*)embed)[i] : f2bf(((const float*)embed)[i]);
    }
    return;
  }
  bid -= SEG1;
  if(bid < SEG2){
    int i0 = (bid*256 + tid)*4;
    int n = B_*T_*ACT_;
    #pragma unroll
    for(int k=0;k<4;k++){
      int i = i0+k;
      if(i < n) actF[i] = dt ? bf2f(((const bf16*)action)[i]) : ((const float*)action)[i];
    }
    return;
  }
  bid -= SEG2;
  if(bid < SEG3){
    transpose_dev(w8, WgT, GRUK_, GRUN_, bid/48, bid%48, 0, dt, ts);
    return;
  }
  bid -= SEG3;
  if(bid < SEG4){
    int head = bid/256, rem = bid%256;
    transpose_dev(w12, W3T, DETER_, HID_, rem/16, rem%16, head, dt, ts);
    return;
  }
  bid -= SEG4;
  transpose_dev(w18, W5T, OBSK_, HID_, bid/16, bid%16, 0, dt, ts);
}

// ---- MFMA GEMM: 128x32 output tile per block, K split over 4 waves, LDS reduce ----
// mode 0 (grid 256):
//   bid<192: z2p[part] = A2[128,2048] @ WgT tile (96 ct x 2 parts, Kc=1024)
//   bid>=192: z5p[2+part] = embB[:,t,:] @ W5T[:,1024:] tile (32 ct x 2 parts, Kc=768)
// mode 1 (grid 128):
//   bid<64:  z3p[part] = deterB @ W3T[idx] tile (32 ct x 2 parts, Kc=512)
//   bid>=64: z5p[part] = deterB @ W5T[:, :1024] tile (32 ct x 2 parts, Kc=512)
__global__ __launch_bounds__(256) void k_gemm(
    int mode, int t,
    const bf16* A2, const bf16* deterB, const bf16* embB,
    const bf16* WgT, const bf16* W3T, const bf16* W5T,
    float* z2p, float* z3p, float* z5p, const int* ens_index)
{
  __shared__ float red[8192];   // 32 KB
  int bid = blockIdx.x;
  const bf16 *A0 = nullptr, *A1 = nullptr, *BT; float* Cdst;
  int N, ldb, s0 = 0, s1 = 0, split = 1<<30, k0, kc;
  if(mode == 0){
    if(bid < 192){
      int ct = bid % 96, part = bid / 96;
      N = GRUN_; ldb = GRUK_; BT = WgT + (size_t)ct*32*GRUK_;
      A0 = A2; s0 = GRUK_;
      k0 = part*1024; kc = 1024;
      Cdst = z2p + (size_t)part*B_*GRUN_ + ct*32;
    } else {
      int b2 = bid - 192;
      int ct = b2 & 31, part = b2 >> 5;
      N = HID_; ldb = OBSK_; BT = W5T + (size_t)ct*32*OBSK_;
      split = DETER_;
      A1 = embB + (size_t)t*EMB_; s1 = T_*EMB_;
      k0 = 1024 + part*768; kc = 768;
      Cdst = z5p + (size_t)(2+part)*B_*HID_ + ct*32;
    }
  } else if(bid < 64){
    int ct = bid & 31, part = bid >> 5;
    int idx = ens_index[t];
    N = HID_; ldb = DETER_; BT = W3T + (size_t)idx*DETER_*HID_ + (size_t)ct*32*DETER_;
    A0 = deterB; s0 = DETER_;
    k0 = part*512; kc = 512;
    Cdst = z3p + (size_t)part*B_*HID_ + ct*32;
  } else {
    int b2 = bid - 64;
    int ct = b2 & 31, part = b2 >> 5;
    N = HID_; ldb = OBSK_; BT = W5T + (size_t)ct*32*OBSK_;
    A0 = deterB; s0 = DETER_;
    k0 = part*512; kc = 512;
    Cdst = z5p + (size_t)part*B_*HID_ + ct*32;
  }
  int tid = threadIdx.x;
  int wave = tid >> 6, lane = tid & 63;
  int quad = lane >> 4, lo = lane & 15;
  int kw0 = k0 + wave*(kc>>2), kw1 = kw0 + (kc>>2);
  f32x4 acc[8][2];
  #pragma unroll
  for(int rf=0;rf<8;rf++){ acc[rf][0]=(f32x4)0.f; acc[rf][1]=(f32x4)0.f; }
  for(int kk=kw0; kk<kw1; kk+=32){
    int kf = kk + quad*8;
    const bf16* Ab; int str, ko;
    if(kf < split){ Ab=A0; str=s0; ko=kf; } else { Ab=A1; str=s1; ko=kf-split; }
    short8 af[8], bfg[2];
    #pragma unroll
    for(int rf=0;rf<8;rf++)
      af[rf] = *(const short8*)(const void*)(Ab + (size_t)(16*rf+lo)*str + ko);
    #pragma unroll
    for(int c=0;c<2;c++)
      bfg[c] = *(const short8*)(const void*)(BT + (size_t)(16*c+lo)*ldb + kf);
    #pragma unroll
    for(int rf=0;rf<8;rf++){
      acc[rf][0] = __builtin_amdgcn_mfma_f32_16x16x32_bf16(af[rf], bfg[0], acc[rf][0], 0,0,0);
      acc[rf][1] = __builtin_amdgcn_mfma_f32_16x16x32_bf16(af[rf], bfg[1], acc[rf][1], 0,0,0);
    }
  }
  // cross-wave reduce: waves 2,3 dump -> waves 0,1 add -> waves 0,1 dump -> all sum pairs
  if(wave >= 2){
    #pragma unroll
    for(int rf=0;rf<8;rf++)
      #pragma unroll
      for(int c=0;c<2;c++)
        *(f32x4*)&red[(((wave-2)*16) + rf*2 + c)*256 + lane*4] = acc[rf][c];
  }
  __syncthreads();
  if(wave < 2){
    #pragma unroll
    for(int rf=0;rf<8;rf++)
      #pragma unroll
      for(int c=0;c<2;c++)
        acc[rf][c] += *(const f32x4*)&red[((wave*16) + rf*2 + c)*256 + lane*4];
  }
  __syncthreads();
  if(wave < 2){
    #pragma unroll
    for(int rf=0;rf<8;rf++)
      #pragma unroll
      for(int c=0;c<2;c++)
        *(f32x4*)&red[((wave*16) + rf*2 + c)*256 + lane*4] = acc[rf][c];
  }
  __syncthreads();
  #pragma unroll
  for(int i=0;i<4;i++){
    int r = (tid>>3) + 32*i;
    int col0 = (tid&7)*4;
    int rf = r>>4, rr = r&15, q = rr>>2, g = rr&3;
    f32x4 v;
    #pragma unroll
    for(int j=0;j<4;j++){
      int col = col0+j; int c = col>>4, lo2 = col&15;
      int lane2 = q*16+lo2;
      v[j] = red[(rf*2 + c)*256 + lane2*4 + g]
           + red[(16 + rf*2 + c)*256 + lane2*4 + g];
    }
    *(f32x4*)(Cdst + (size_t)r*N + col0) = v;
  }
}

// ---- reduce z2 parts + bias, LN over 3072, GRU -> deter (1024 threads, h=tid) ----
__global__ __launch_bounds__(1024) void k_gru(
    const float* z2p, const float* paramF, const int* dflag,
    const float* determ, float* deter, bf16* deterB, void* out, int t)
{
  __shared__ float sm[32];
  int b = blockIdx.x, tid = threadIdx.x;
  int dt = dflag[0];
  float zz[3]; float s=0.f, s2=0.f;
  #pragma unroll
  for(int i=0;i<3;i++){
    int h = tid + 1024*i;
    float acc = paramF[Pbg + h]
              + z2p[(size_t)b*GRUN_ + h]
              + z2p[(size_t)(B_ + b)*GRUN_ + h];
    zz[i]=acc; s+=acc; s2+=acc*acc;
  }
  block_reduce2w(s, s2, sm, 16);
  float mean = s/GRUN_, var = s2/GRUN_ - mean*mean;
  float rstd = rsqrtf(fmaxf(var,0.f) + 1e-5f);
  {
    float lnr = (zz[0] - mean)*rstd*paramF[Pgg+tid     ] + paramF[Pbng+tid     ];
    float lnc = (zz[1] - mean)*rstd*paramF[Pgg+tid+1024] + paramF[Pbng+tid+1024];
    float lnu = (zz[2] - mean)*rstd*paramF[Pgg+tid+2048] + paramF[Pbng+tid+2048];
    float reset = sigm_(lnr);
    float cand  = tanhf(reset*lnc);
    float upd   = sigm_(lnu - 1.f);          // UPDATE_BIAS
    float dn = upd*cand + (1.f-upd)*determ[b*DETER_+tid];
    deter[b*DETER_+tid]  = dn;
    deterB[b*DETER_+tid] = f2bf(dn);
    stout(out, dt, ((size_t)b*T_+t)*OUTW_ + 192 + tid, dn);
  }
}

// ---- tail: heads + outputs + step_in(t+1) (1024 threads, h=tid) ----
__global__ __launch_bounds__(1024) void k_tail(
    const float* z3p, const float* z5p, const float* paramF, const int* dflag,
    const float* actF, const void* isf,
    const float* deter, float* determ, bf16* A2,
    void* out, const int* ens_index, int t)
{
  __shared__ float hs[1024], xo[1024];
  __shared__ float red[1024];
  __shared__ float dsO[128];
  __shared__ float in44[48];
  __shared__ float sm[32];
  int b = blockIdx.x, tid = threadIdx.x;
  int dt = dflag[0];
  int idx = ens_index[t];
  float a3 = z3p[(size_t)b*HID_ + tid] + z3p[(size_t)(B_ + b)*HID_ + tid]
           + paramF[Pb3 + idx*HID_ + tid];
  float a5 = z5p[(size_t)b*HID_ + tid] + z5p[(size_t)(B_ + b)*HID_ + tid]
           + z5p[(size_t)(2*B_ + b)*HID_ + tid] + z5p[(size_t)(3*B_ + b)*HID_ + tid]
           + paramF[Pb5 + tid];
  float s3=a3, q3=a3*a3, s5=a5, q5=a5*a5;
  block_reduce2w(s3, q3, sm, 16);
  block_reduce2w(s5, q5, sm, 16);
  float m3=s3/HID_, v3=q3/HID_-m3*m3, r3=rsqrtf(fmaxf(v3,0.f)+1e-5f);
  float m5=s5/HID_, v5=q5/HID_-m5*m5, r5=rsqrtf(fmaxf(v5,0.f)+1e-5f);
  hs[tid] = elu_((a3-m3)*r3*paramF[Pg3+idx*HID_+tid] + paramF[Pbn3+idx*HID_+tid]);
  xo[tid] = elu_((a5-m5)*r5*paramF[Pg5+tid] + paramF[Pbn5+tid]);
  __syncthreads();
  int j = tid & 63, cch = tid >> 6;   // 16 chunks of 64
  {
    const float* W = paramF + PW4 + (size_t)idx*HID_*64;
    float a = 0.f;
    for(int k=cch*64; k<cch*64+64; k++) a += hs[k]*W[k*64 + j];
    red[tid] = a;
    __syncthreads();
    if(tid < 64){
      float acc = paramF[Pb4+idx*64+tid];
      for(int c=0;c<16;c++) acc += red[c*64+tid];
      dsO[tid] = acc;
    }
    __syncthreads();
    const float* W6f = paramF + PW6;
    a = 0.f;
    for(int k=cch*64; k<cch*64+64; k++) a += xo[k]*W6f[k*64 + j];
    red[tid] = a;
    __syncthreads();
    if(tid < 64){
      float acc = paramF[Pb6+tid];
      for(int c=0;c<16;c++) acc += red[c*64+tid];
      dsO[64+tid] = acc;
    }
    __syncthreads();
  }
  size_t ob = ((size_t)b*T_ + t)*OUTW_;
  if(tid < 32){
    float pm = dsO[tid];
    float ps = softplus_(dsO[32+tid]) + 0.1f;
    float om = dsO[64+tid];
    float os = softplus_(dsO[96+tid]) + 0.1f;
    stout(out, dt, ob+tid,      om);   // omean
    stout(out, dt, ob+32+tid,   os);   // ostd
    stout(out, dt, ob+64+tid,   om);   // post_stoch
    stout(out, dt, ob+96+tid,   pm);   // pmean
    stout(out, dt, ob+128+tid,  ps);   // pstd
    stout(out, dt, ob+160+tid,  pm);   // prior_stoch
  }
  // ---- step_in for t+1 (block-local stoch carry = dsO[64..95]) ----
  if(t+1 < T_){
    float m = maskv(isf, dflag[1], b*T_ + (t+1));
    if(tid < 32)       in44[tid] = dsO[64+tid]*m;
    else if(tid < 44)  in44[tid] = actF[(size_t)(b*T_+(t+1))*ACT_ + (tid-32)]*m;
    __syncthreads();
    const float* W1f = paramF + PW1;
    float acc = paramF[Pb1 + tid];
    for(int k=0;k<STOCH_+ACT_;k++) acc += in44[k]*W1f[k*HID_ + tid];
    float s = acc, s2 = acc*acc;
    block_reduce2w(s, s2, sm, 16);
    float mean = s/HID_, var = s2/HID_ - mean*mean;
    float rstd = rsqrtf(fmaxf(var,0.f) + 1e-5f);
    float xv = (acc-mean)*rstd*paramF[Pg1+tid] + paramF[Pbn1+tid];
    A2[(size_t)b*GRUK_ + tid] = f2bf(elu_(xv));
    float dm = deter[b*DETER_+tid]*m;
    determ[b*DETER_+tid] = dm;
    A2[(size_t)b*GRUK_ + HID_ + tid] = f2bf(dm);
  }
}

// ---- init: step_in for t=0 with zero carry state (1024 threads) ----
__global__ __launch_bounds__(1024) void k_init(
    const float* actF, const void* isf, const int* dflag,
    const float* paramF, float* determ, bf16* A2)
{
  __shared__ float in44[48];
  __shared__ float sm[32];
  int b = blockIdx.x, tid = threadIdx.x;
  float m = maskv(isf, dflag[1], b*T_);
  if(tid < 32)       in44[tid] = 0.f;
  else if(tid < 44)  in44[tid] = actF[(size_t)(b*T_)*ACT_ + (tid-32)]*m;
  __syncthreads();
  const float* W1f = paramF + PW1;
  float acc = paramF[Pb1 + tid];
  for(int k=0;k<STOCH_+ACT_;k++) acc += in44[k]*W1f[k*HID_ + tid];
  float s = acc, s2 = acc*acc;
  block_reduce2w(s, s2, sm, 16);
  float mean = s/HID_, var = s2/HID_ - mean*mean;
  float rstd = rsqrtf(fmaxf(var,0.f) + 1e-5f);
  float xv = (acc-mean)*rstd*paramF[Pg1+tid] + paramF[Pbn1+tid];
  A2[(size_t)b*GRUK_ + tid] = f2bf(elu_(xv));
  determ[b*DETER_+tid] = 0.f;
  A2[(size_t)b*GRUK_ + HID_ + tid] = f2bf(0.f);
}

extern "C" void kernel_launch(void* const* d_in, const int* in_sizes, int n_in,
                              void* d_out, int out_size, void* d_ws, size_t ws_size,
                              hipStream_t stream)
{
  const void* embed  = d_in[0];
  const void* action = d_in[1];
  const void* isf    = d_in[2];
  const int*  ens_ix = (const int*)d_in[3];

  char* ws = (char*)d_ws;
  float* deter  = (float*)(ws + 0);            // 512 KB
  float* determ = (float*)(ws + 524288);       // 512 KB
  bf16*  A2     = (bf16*) (ws + 1048576);      // 512 KB
  bf16*  deterB = (bf16*) (ws + 1572864);      // 256 KB
  float* z2p    = (float*)(ws + 1835008);      // 3 MB   (2 parts x 128x3072 f32)
  float* z3p    = (float*)(ws + 4980736);      // 1 MB   (2 parts x 128x1024 f32)
  float* z5p    = (float*)(ws + 6029312);      // 2 MB   (4 parts: 2 deter + 2 emb)
  bf16*  WgT    = (bf16*) (ws + 8126464);      // 12.58 MB
  bf16*  W3T    = (bf16*) (ws + 20709376);     // 10.49 MB
  bf16*  W5T    = (bf16*) (ws + 31195136);     // 5.24 MB
  float* paramF = (float*)(ws + 36438016);     // 1.88 MB
  bf16*  embB   = (bf16*) (ws + 38315520);     // 25.17 MB
  float* actF   = (float*)(ws + 63481344);     // 0.39 MB
  int*   dflag  = (int*)  (ws + 63874560);

  k_detect<<<2,256,0,stream>>>((const unsigned short*)embed, (const unsigned char*)isf, dflag);

  PDesc pd;
  const int srcidx[17] = {4,5,6,7, 9,10,11, 13,14,15, 17, 19,20,21, 23, 16, 22};
  const int sizes[17]  = {45056,1024,1024,1024, 3072,3072,3072, 5120,5120,5120,
                          320, 1024,1024,1024, 64, 327680, 65536};
  int cum = 0;
  for(int i=0;i<17;i++){ pd.src[i] = d_in[srcidx[i]]; pd.cum[i] = cum; cum += sizes[i]; }
  pd.cum[17] = cum;  // 469376

  int setup_grid = SEG0 + SEG1 + SEG2 + SEG3 + SEG4 + SEG5;   // 17674
  k_setup<<<setup_grid,256,0,stream>>>(pd, paramF, dflag,
                                       embed, embB, action, actF,
                                       d_in[8], WgT, d_in[12], W3T, d_in[18], W5T);

  k_init<<<B_,1024,0,stream>>>(actF, isf, dflag, paramF, determ, A2);

  for(int t=0; t<T_; t++){
    k_gemm<<<256,256,0,stream>>>(0, t, A2, deterB, embB, WgT, W3T, W5T, z2p, z3p, z5p, ens_ix);
    k_gru<<<B_,1024,0,stream>>>(z2p, paramF, dflag, determ, deter, deterB, d_out, t);
    k_gemm<<<128,256,0,stream>>>(1, t, A2, deterB, embB, WgT, W3T, W5T, z2p, z3p, z5p, ens_ix);
    k_tail<<<B_,1024,0,stream>>>(z3p, z5p, paramF, dflag, actF, isf, deter, determ, A2, d_out, ens_ix, t);
  }
}